// Round 1
// baseline (1097.812 us; speedup 1.0000x reference)
//
#include <hip/hip_runtime.h>
#include <cstdint>
#include <cstddef>

#define B_ 32
#define N_ 512
#define H_ 256
#define S_ 3
#define BN_ (B_*N_)            // 16384
#define BIGF 3.4028234e+38f
#define EPSF 1e-5f

// ---------------- f = x * mask_row (per-row broadcast), float4 ----------------
__global__ __launch_bounds__(256) void mask_mul_k(
    const float* __restrict__ x, const float* __restrict__ masks, float* __restrict__ f) {
  int i = blockIdx.x * 256 + threadIdx.x;   // float4 index; H_/4 = 64 float4 per row
  int row = i >> 6;
  float m = masks[row];
  float4 v = ((const float4*)x)[i];
  v.x *= m; v.y *= m; v.z *= m; v.w *= m;
  ((float4*)f)[i] = v;
}

// ---------------- float4 copy ----------------
__global__ __launch_bounds__(256) void copy_k(
    const float* __restrict__ src, float* __restrict__ dst) {
  int i = blockIdx.x * 256 + threadIdx.x;
  ((float4*)dst)[i] = ((const float4*)src)[i];
}

// ---------------- C[M,Nn] = A[M,K] @ W[Nn,K]^T (+bias)(+relu) ----------------
// 64x64 tile, 256 threads, 4x4 microtile, K-tile 16. LDS stride 68 (16B-aligned, 2-way max).
template<int EPI>  // 0 = none, 1 = +bias, 2 = +bias+relu
__global__ __launch_bounds__(256) void gemm_bt_k(
    const float* __restrict__ A, const float* __restrict__ W,
    const float* __restrict__ bias, float* __restrict__ C,
    int M, int K, int Nn) {
  __shared__ float As[16][68];
  __shared__ float Ws[16][68];
  const int t = threadIdx.x;
  const int tx = t & 15, ty = t >> 4;
  const int m0 = blockIdx.y * 64, n0 = blockIdx.x * 64;
  const int lr = t >> 2, lc = (t & 3) << 2;
  float acc[4][4] = {};
  for (int k0 = 0; k0 < K; k0 += 16) {
    float4 av = *(const float4*)(A + (size_t)(m0 + lr) * K + k0 + lc);
    float4 wv = *(const float4*)(W + (size_t)(n0 + lr) * K + k0 + lc);
    __syncthreads();
    As[lc+0][lr] = av.x; As[lc+1][lr] = av.y; As[lc+2][lr] = av.z; As[lc+3][lr] = av.w;
    Ws[lc+0][lr] = wv.x; Ws[lc+1][lr] = wv.y; Ws[lc+2][lr] = wv.z; Ws[lc+3][lr] = wv.w;
    __syncthreads();
#pragma unroll
    for (int kk = 0; kk < 16; ++kk) {
      float a0 = As[kk][ty*4+0], a1 = As[kk][ty*4+1], a2 = As[kk][ty*4+2], a3 = As[kk][ty*4+3];
      float w0 = Ws[kk][tx*4+0], w1 = Ws[kk][tx*4+1], w2 = Ws[kk][tx*4+2], w3 = Ws[kk][tx*4+3];
      acc[0][0] += a0*w0; acc[0][1] += a0*w1; acc[0][2] += a0*w2; acc[0][3] += a0*w3;
      acc[1][0] += a1*w0; acc[1][1] += a1*w1; acc[1][2] += a1*w2; acc[1][3] += a1*w3;
      acc[2][0] += a2*w0; acc[2][1] += a2*w1; acc[2][2] += a2*w2; acc[2][3] += a2*w3;
      acc[3][0] += a3*w0; acc[3][1] += a3*w1; acc[3][2] += a3*w2; acc[3][3] += a3*w3;
    }
  }
  float4 bv = {0.f, 0.f, 0.f, 0.f};
  if (EPI >= 1) bv = *(const float4*)(bias + n0 + tx*4);
#pragma unroll
  for (int i = 0; i < 4; ++i) {
    float4 c;
    c.x = acc[i][0] + bv.x; c.y = acc[i][1] + bv.y;
    c.z = acc[i][2] + bv.z; c.w = acc[i][3] + bv.w;
    if (EPI == 2) {
      c.x = fmaxf(c.x, 0.f); c.y = fmaxf(c.y, 0.f);
      c.z = fmaxf(c.z, 0.f); c.w = fmaxf(c.w, 0.f);
    }
    *(float4*)(C + (size_t)(m0 + ty*4 + i) * Nn + n0 + tx*4) = c;
  }
}

// ---------------- logits[b,m,n] = (q.k)*scale - am[b,n] - infmask[b,m,n], batched ----------------
__global__ __launch_bounds__(256) void qk_logits_k(
    const float* __restrict__ Q, const float* __restrict__ Kin,
    const float* __restrict__ masks, const float* __restrict__ guide,
    float* __restrict__ out) {
  const int b = blockIdx.z;
  const float* A = Q  + (size_t)b * N_ * H_;
  const float* W = Kin + (size_t)b * N_ * H_;
  __shared__ float As[16][68];
  __shared__ float Ws[16][68];
  const int t = threadIdx.x;
  const int tx = t & 15, ty = t >> 4;
  const int m0 = blockIdx.y * 64, n0 = blockIdx.x * 64;
  const int lr = t >> 2, lc = (t & 3) << 2;
  float acc[4][4] = {};
  for (int k0 = 0; k0 < H_; k0 += 16) {
    float4 av = *(const float4*)(A + (size_t)(m0 + lr) * H_ + k0 + lc);
    float4 wv = *(const float4*)(W + (size_t)(n0 + lr) * H_ + k0 + lc);
    __syncthreads();
    As[lc+0][lr] = av.x; As[lc+1][lr] = av.y; As[lc+2][lr] = av.z; As[lc+3][lr] = av.w;
    Ws[lc+0][lr] = wv.x; Ws[lc+1][lr] = wv.y; Ws[lc+2][lr] = wv.z; Ws[lc+3][lr] = wv.w;
    __syncthreads();
#pragma unroll
    for (int kk = 0; kk < 16; ++kk) {
      float a0 = As[kk][ty*4+0], a1 = As[kk][ty*4+1], a2 = As[kk][ty*4+2], a3 = As[kk][ty*4+3];
      float w0 = Ws[kk][tx*4+0], w1 = Ws[kk][tx*4+1], w2 = Ws[kk][tx*4+2], w3 = Ws[kk][tx*4+3];
      acc[0][0] += a0*w0; acc[0][1] += a0*w1; acc[0][2] += a0*w2; acc[0][3] += a0*w3;
      acc[1][0] += a1*w0; acc[1][1] += a1*w1; acc[1][2] += a1*w2; acc[1][3] += a1*w3;
      acc[2][0] += a2*w0; acc[2][1] += a2*w1; acc[2][2] += a2*w2; acc[2][3] += a2*w3;
      acc[3][0] += a3*w0; acc[3][1] += a3*w1; acc[3][2] += a3*w2; acc[3][3] += a3*w3;
    }
  }
  const float scale = 0.0625f;  // 1/sqrt(H_)
  float4 mv = *(const float4*)(masks + (size_t)b * N_ + n0 + tx*4);
  float4 am;
  am.x = (mv.x != 0.f) ? 0.f : BIGF; am.y = (mv.y != 0.f) ? 0.f : BIGF;
  am.z = (mv.z != 0.f) ? 0.f : BIGF; am.w = (mv.w != 0.f) ? 0.f : BIGF;
#pragma unroll
  for (int i = 0; i < 4; ++i) {
    int m = m0 + ty*4 + i;
    const float4 g4 = *(const float4*)(guide + ((size_t)b * N_ + m) * N_ + n0 + tx*4);
    float4 c;
    c.x = acc[i][0]*scale - am.x - ((g4.x != 0.f) ? 0.f : BIGF);
    c.y = acc[i][1]*scale - am.y - ((g4.y != 0.f) ? 0.f : BIGF);
    c.z = acc[i][2]*scale - am.z - ((g4.z != 0.f) ? 0.f : BIGF);
    c.w = acc[i][3]*scale - am.w - ((g4.w != 0.f) ? 0.f : BIGF);
    *(float4*)(out + ((size_t)b * N_ + m) * N_ + n0 + tx*4) = c;
  }
}

// ---------------- in-place row softmax over N_=512, one wave per row ----------------
__global__ __launch_bounds__(256) void softmax_k(float* __restrict__ att) {
  const int row  = blockIdx.x * 4 + (threadIdx.x >> 6);
  const int lane = threadIdx.x & 63;
  float* p = att + (size_t)row * N_ + lane * 8;
  float4 v0 = *(float4*)p;
  float4 v1 = *(float4*)(p + 4);
  float mx = fmaxf(fmaxf(fmaxf(v0.x, v0.y), fmaxf(v0.z, v0.w)),
                   fmaxf(fmaxf(v1.x, v1.y), fmaxf(v1.z, v1.w)));
#pragma unroll
  for (int off = 1; off < 64; off <<= 1) mx = fmaxf(mx, __shfl_xor(mx, off));
  v0.x = __expf(v0.x - mx); v0.y = __expf(v0.y - mx);
  v0.z = __expf(v0.z - mx); v0.w = __expf(v0.w - mx);
  v1.x = __expf(v1.x - mx); v1.y = __expf(v1.y - mx);
  v1.z = __expf(v1.z - mx); v1.w = __expf(v1.w - mx);
  float s = v0.x + v0.y + v0.z + v0.w + v1.x + v1.y + v1.z + v1.w;
#pragma unroll
  for (int off = 1; off < 64; off <<= 1) s += __shfl_xor(s, off);
  float inv = 1.f / s;
  v0.x *= inv; v0.y *= inv; v0.z *= inv; v0.w *= inv;
  v1.x *= inv; v1.y *= inv; v1.z *= inv; v1.w *= inv;
  *(float4*)p = v0;
  *(float4*)(p + 4) = v1;
}

// ---------------- y = LayerNorm(y + res) over H_=256, one wave per row ----------------
__global__ __launch_bounds__(256) void add_ln_k(
    float* __restrict__ y, const float* __restrict__ res) {
  const int row  = blockIdx.x * 4 + (threadIdx.x >> 6);
  const int lane = threadIdx.x & 63;
  float*       py = y   + (size_t)row * H_ + lane * 4;
  const float* pr = res + (size_t)row * H_ + lane * 4;
  float4 a = *(float4*)py;
  float4 r = *(const float4*)pr;
  a.x += r.x; a.y += r.y; a.z += r.z; a.w += r.w;
  float s = a.x + a.y + a.z + a.w;
#pragma unroll
  for (int off = 1; off < 64; off <<= 1) s += __shfl_xor(s, off);
  float mu = s * (1.f / H_);
  float dx = a.x - mu, dy = a.y - mu, dz = a.z - mu, dw = a.w - mu;
  float ss = dx*dx + dy*dy + dz*dz + dw*dw;
#pragma unroll
  for (int off = 1; off < 64; off <<= 1) ss += __shfl_xor(ss, off);
  float var = ss * (1.f / H_);
  float inv = 1.f / sqrtf(var + EPSF);
  float4 o;
  o.x = dx * inv; o.y = dy * inv; o.z = dz * inv; o.w = dw * inv;
  *(float4*)py = o;
}

// ---------------- C[b] = A[b][M,K] @ Bm[b][K,Nn]  (att @ v), batched ----------------
__global__ __launch_bounds__(256) void gemm_nn_k(
    const float* __restrict__ Aall, const float* __restrict__ Ball,
    float* __restrict__ Call, int M, int K, int Nn,
    long sA, long sB, long sC) {
  const int b = blockIdx.z;
  const float* A  = Aall + (size_t)b * sA;
  const float* Bm = Ball + (size_t)b * sB;
  float*       C  = Call + (size_t)b * sC;
  __shared__ float As[16][68];
  __shared__ float Bs[16][68];
  const int t = threadIdx.x;
  const int tx = t & 15, ty = t >> 4;
  const int m0 = blockIdx.y * 64, n0 = blockIdx.x * 64;
  const int lr = t >> 2, lc = (t & 3) << 2;   // A: 64 rows x 16 k
  const int br = t >> 4, bc = (t & 15) << 2;  // B: 16 k-rows x 64 cols
  float acc[4][4] = {};
  for (int k0 = 0; k0 < K; k0 += 16) {
    float4 av = *(const float4*)(A  + (size_t)(m0 + lr) * K + k0 + lc);
    float4 bv = *(const float4*)(Bm + (size_t)(k0 + br) * Nn + n0 + bc);
    __syncthreads();
    As[lc+0][lr] = av.x; As[lc+1][lr] = av.y; As[lc+2][lr] = av.z; As[lc+3][lr] = av.w;
    *(float4*)&Bs[br][bc] = bv;
    __syncthreads();
#pragma unroll
    for (int kk = 0; kk < 16; ++kk) {
      float a0 = As[kk][ty*4+0], a1 = As[kk][ty*4+1], a2 = As[kk][ty*4+2], a3 = As[kk][ty*4+3];
      float w0 = Bs[kk][tx*4+0], w1 = Bs[kk][tx*4+1], w2 = Bs[kk][tx*4+2], w3 = Bs[kk][tx*4+3];
      acc[0][0] += a0*w0; acc[0][1] += a0*w1; acc[0][2] += a0*w2; acc[0][3] += a0*w3;
      acc[1][0] += a1*w0; acc[1][1] += a1*w1; acc[1][2] += a1*w2; acc[1][3] += a1*w3;
      acc[2][0] += a2*w0; acc[2][1] += a2*w1; acc[2][2] += a2*w2; acc[2][3] += a2*w3;
      acc[3][0] += a3*w0; acc[3][1] += a3*w1; acc[3][2] += a3*w2; acc[3][3] += a3*w3;
    }
  }
#pragma unroll
  for (int i = 0; i < 4; ++i) {
    float4 c;
    c.x = acc[i][0]; c.y = acc[i][1]; c.z = acc[i][2]; c.w = acc[i][3];
    *(float4*)(C + (size_t)(m0 + ty*4 + i) * Nn + n0 + tx*4) = c;
  }
}

extern "C" void kernel_launch(void* const* d_in, const int* in_sizes, int n_in,
                              void* d_out, int out_size, void* d_ws, size_t ws_size,
                              hipStream_t stream) {
  const float* features = (const float*)d_in[0];
  const float* masks    = (const float*)d_in[1];
  const float* guide    = (const float*)d_in[2];
  const float* prior    = (const float*)d_in[3];
  const float* WQ       = (const float*)d_in[4];
  const float* WK       = (const float*)d_in[5];
  const float* WV       = (const float*)d_in[6];
  const float* W1       = (const float*)d_in[7];
  const float* b1       = (const float*)d_in[8];
  const float* W2       = (const float*)d_in[9];
  const float* b2       = (const float*)d_in[10];

  float* out     = (float*)d_out;
  float* out_x   = out;                          // BN_*H_ = 4,194,304
  float* out_att = out + (size_t)BN_ * H_;       // 3 * B_*N_*N_

  const size_t SZ = (size_t)BN_ * H_;            // 16 MB each in fp32
  float* ws   = (float*)d_ws;
  float* f    = ws;
  float* q    = ws + SZ;
  float* kbuf = ws + 2 * SZ;
  float* v    = ws + 3 * SZ;
  float* x    = ws + 4 * SZ;
  float* post = kbuf;   // alias: k dead after qk_logits
  float* t1   = q;      // alias: q dead after qk_logits

  dim3 blk(256);
  dim3 g_ew(BN_ * H_ / 4 / 256);        // 4096
  dim3 g_gemm(H_ / 64, BN_ / 64);       // (4, 256)
  dim3 g_qk(N_ / 64, N_ / 64, B_);      // (8, 8, 32)
  dim3 g_pv(H_ / 64, N_ / 64, B_);      // (4, 8, 32)
  dim3 g_row(BN_ / 4);                  // 4096 (wave-per-row kernels)
  dim3 g_copy((size_t)B_ * N_ * N_ / 4 / 256);  // 8192

  const float* xin = features;
  for (int i = 0; i < S_; ++i) {
    mask_mul_k<<<g_ew, blk, 0, stream>>>(xin, masks, f);
    float* att = out_att + (size_t)i * B_ * N_ * N_;
    if (i == 0) {
      copy_k<<<g_copy, blk, 0, stream>>>(prior, att);
    } else {
      gemm_bt_k<0><<<g_gemm, blk, 0, stream>>>(f, WQ + (size_t)i*H_*H_, nullptr, q,    BN_, H_, H_);
      gemm_bt_k<0><<<g_gemm, blk, 0, stream>>>(f, WK + (size_t)i*H_*H_, nullptr, kbuf, BN_, H_, H_);
      qk_logits_k<<<g_qk, blk, 0, stream>>>(q, kbuf, masks, guide, att);
      softmax_k<<<g_row, blk, 0, stream>>>(att);
    }
    gemm_bt_k<0><<<g_gemm, blk, 0, stream>>>(f, WV + (size_t)i*H_*H_, nullptr, v, BN_, H_, H_);
    // post_raw = att @ v
    gemm_nn_k<<<g_pv, blk, 0, stream>>>(att, v, post, N_, N_, H_,
                                        (long)N_ * N_, (long)N_ * H_, (long)N_ * H_);
    // post = LN(post_raw + f)
    add_ln_k<<<g_row, blk, 0, stream>>>(post, f);
    // ffn1 = relu(post @ W1^T + b1)
    gemm_bt_k<2><<<g_gemm, blk, 0, stream>>>(post, W1 + (size_t)i*H_*H_, b1 + (size_t)i*H_, t1, BN_, H_, H_);
    // x = ffn1 @ W2^T + b2
    gemm_bt_k<1><<<g_gemm, blk, 0, stream>>>(t1, W2 + (size_t)i*H_*H_, b2 + (size_t)i*H_, x, BN_, H_, H_);
    // x = LN(x + post)
    add_ln_k<<<g_row, blk, 0, stream>>>(x, post);
    xin = x;
  }
  mask_mul_k<<<g_ew, blk, 0, stream>>>(x, masks, out_x);
}

// Round 2
// 549.362 us; speedup vs baseline: 1.9983x; 1.9983x over previous
//
#include <hip/hip_runtime.h>
#include <cstdint>
#include <cstddef>

#define B_ 32
#define N_ 512
#define H_ 256
#define S_ 3
#define BN_ (B_*N_)            // 16384
#define BIGF 3.4028234e+38f
#define EPSF 1e-5f

typedef __bf16 bf16x8 __attribute__((ext_vector_type(8)));
typedef float  f32x4  __attribute__((ext_vector_type(4)));

__device__ __forceinline__ unsigned short f2bf(float f) {
  __bf16 h = (__bf16)f;             // RNE convert
  unsigned short s;
  __builtin_memcpy(&s, &h, 2);
  return s;
}
__device__ __forceinline__ float bf2f(unsigned short u) {
  unsigned int v = ((unsigned int)u) << 16;
  float f;
  __builtin_memcpy(&f, &v, 4);
  return f;
}

// ---------------- fp32 -> bf16 convert (float4 / ushort4) ----------------
__global__ __launch_bounds__(256) void cvt_bf16_k(
    const float* __restrict__ in, unsigned short* __restrict__ out) {
  int i = blockIdx.x * 256 + threadIdx.x;
  float4 v = ((const float4*)in)[i];
  ushort4 o;
  o.x = f2bf(v.x); o.y = f2bf(v.y); o.z = f2bf(v.z); o.w = f2bf(v.w);
  ((ushort4*)out)[i] = o;
}

// ---------------- f = x * mask_row ; OUT_BF: bf16 out, else fp32 out ----------------
template<int OUT_BF>
__global__ __launch_bounds__(256) void mask_mul_k(
    const float* __restrict__ x, const float* __restrict__ masks,
    float* __restrict__ fo, unsigned short* __restrict__ fb) {
  int i = blockIdx.x * 256 + threadIdx.x;   // float4 index; H_/4 = 64 per row
  int row = i >> 6;
  float m = masks[row];
  float4 v = ((const float4*)x)[i];
  v.x *= m; v.y *= m; v.z *= m; v.w *= m;
  if (OUT_BF) {
    ushort4 o;
    o.x = f2bf(v.x); o.y = f2bf(v.y); o.z = f2bf(v.z); o.w = f2bf(v.w);
    ((ushort4*)fb)[i] = o;
  } else {
    ((float4*)fo)[i] = v;
  }
}

// ---------------- prior -> att fp32 + att bf16 ----------------
__global__ __launch_bounds__(256) void copy_cvt_k(
    const float* __restrict__ src, float* __restrict__ dstf,
    unsigned short* __restrict__ dstb) {
  int i = blockIdx.x * 256 + threadIdx.x;
  float4 v = ((const float4*)src)[i];
  ((float4*)dstf)[i] = v;
  ushort4 o;
  o.x = f2bf(v.x); o.y = f2bf(v.y); o.z = f2bf(v.z); o.w = f2bf(v.w);
  ((ushort4*)dstb)[i] = o;
}

// ================= MFMA GEMM: C = A(bf16,[m][k]) @ B(bf16,[n][k])^T =================
// 128x128 tile, BK=32, 256 threads (4 waves 2x2), 4x4 grid of 16x16x32 mfma per wave.
// EPI: 0 = bf16 out; 1 = qk logits (scale/mask/guide, fp32 out); 2 = fp32 out;
//      3 = bias+relu -> bf16; 4 = bias -> fp32.
template<int EPI>
__global__ __launch_bounds__(256) void mfma_gemm_k(
    const unsigned short* __restrict__ A, const unsigned short* __restrict__ Bm,
    const float* __restrict__ bias, const float* __restrict__ masks,
    const float* __restrict__ guide,
    float* __restrict__ Cf, unsigned short* __restrict__ Cb,
    int M, int K, int Nn, long sA, long sB, long sC) {
  __shared__ __align__(16) unsigned short As[128 * 40];  // pad to 40 shorts (80B, 16B-aligned)
  __shared__ __align__(16) unsigned short Bs[128 * 40];
  const int b = blockIdx.z;
  const unsigned short* Ap = A + (size_t)b * sA;
  const unsigned short* Bp = Bm + (size_t)b * sB;
  const int t = threadIdx.x;
  const int wave = t >> 6, lane = t & 63;
  const int wm = wave >> 1, wn = wave & 1;
  const int quad = lane >> 4, l15 = lane & 15;
  const int m0 = blockIdx.y * 128, n0 = blockIdx.x * 128;
  const int srow = t >> 1, soff = (t & 1) * 16;   // each thread stages 32B of A and B

  f32x4 acc[4][4];
#pragma unroll
  for (int i = 0; i < 4; ++i)
#pragma unroll
    for (int j = 0; j < 4; ++j) acc[i][j] = (f32x4){0.f, 0.f, 0.f, 0.f};

  const unsigned short* pa = Ap + (size_t)(m0 + srow) * K + soff;
  const unsigned short* pb = Bp + (size_t)(n0 + srow) * K + soff;
  unsigned short* wsa = &As[srow * 40 + soff];
  unsigned short* wsb = &Bs[srow * 40 + soff];

  for (int k0 = 0; k0 < K; k0 += 32) {
    uint4 a0 = *(const uint4*)(pa + k0);
    uint4 a1 = *(const uint4*)(pa + k0 + 8);
    uint4 b0 = *(const uint4*)(pb + k0);
    uint4 b1 = *(const uint4*)(pb + k0 + 8);
    __syncthreads();
    *(uint4*)wsa = a0; *(uint4*)(wsa + 8) = a1;
    *(uint4*)wsb = b0; *(uint4*)(wsb + 8) = b1;
    __syncthreads();
    bf16x8 af[4], bfr[4];
#pragma unroll
    for (int i = 0; i < 4; ++i)
      af[i] = *(const bf16x8*)&As[(wm * 64 + i * 16 + l15) * 40 + quad * 8];
#pragma unroll
    for (int j = 0; j < 4; ++j)
      bfr[j] = *(const bf16x8*)&Bs[(wn * 64 + j * 16 + l15) * 40 + quad * 8];
#pragma unroll
    for (int i = 0; i < 4; ++i)
#pragma unroll
      for (int j = 0; j < 4; ++j)
        acc[i][j] = __builtin_amdgcn_mfma_f32_16x16x32_bf16(af[i], bfr[j], acc[i][j], 0, 0, 0);
  }

  // ---- epilogue ----
  float bv[4];
  if (EPI == 3 || EPI == 4) {
#pragma unroll
    for (int j = 0; j < 4; ++j) bv[j] = bias[n0 + wn * 64 + j * 16 + l15];
  }
  float am[4];
  if (EPI == 1) {
#pragma unroll
    for (int j = 0; j < 4; ++j) {
      float mv = masks[(size_t)b * N_ + n0 + wn * 64 + j * 16 + l15];
      am[j] = (mv != 0.f) ? 0.f : BIGF;
    }
  }
#pragma unroll
  for (int i = 0; i < 4; ++i) {
    const int rbase = m0 + wm * 64 + i * 16 + quad * 4;
#pragma unroll
    for (int j = 0; j < 4; ++j) {
      const int c = n0 + wn * 64 + j * 16 + l15;
#pragma unroll
      for (int r = 0; r < 4; ++r) {
        const int m = rbase + r;
        float val = acc[i][j][r];
        if (EPI == 1) {
          float g = guide[((size_t)b * N_ + m) * N_ + c];
          val = val * 0.0625f - am[j] - ((g != 0.f) ? 0.f : BIGF);
          Cf[(size_t)b * sC + (size_t)m * Nn + c] = val;
        } else if (EPI == 2) {
          Cf[(size_t)b * sC + (size_t)m * Nn + c] = val;
        } else if (EPI == 3) {
          Cb[(size_t)b * sC + (size_t)m * Nn + c] = f2bf(fmaxf(val + bv[j], 0.f));
        } else if (EPI == 4) {
          Cf[(size_t)b * sC + (size_t)m * Nn + c] = val + bv[j];
        } else {
          Cb[(size_t)b * sC + (size_t)m * Nn + c] = f2bf(val);
        }
      }
    }
  }
}

// ---------------- per-batch transpose: vT[b][n][k] = v[b][k][n], bf16, 64x64 tiles ----------------
__global__ __launch_bounds__(256) void transpose_k(
    const unsigned short* __restrict__ v, unsigned short* __restrict__ vt) {
  __shared__ __align__(16) unsigned short Ts[64 * 80];
  const int b = blockIdx.z;
  const int n0 = blockIdx.x * 64, k0 = blockIdx.y * 64;
  const int t = threadIdx.x;
  const int r = t >> 2, c16 = (t & 3) * 16;
  const unsigned short* p = v + ((size_t)b * N_ + k0 + r) * H_ + n0 + c16;
  uint4 u0 = *(const uint4*)p;
  uint4 u1 = *(const uint4*)(p + 8);
  unsigned short e[16];
  *(uint4*)&e[0] = u0; *(uint4*)&e[8] = u1;
#pragma unroll
  for (int q = 0; q < 16; ++q) Ts[(c16 + q) * 80 + r] = e[q];
  __syncthreads();
  unsigned short* dst = vt + ((size_t)b * H_ + n0 + r) * N_ + k0 + c16;
  *(uint4*)dst       = *(const uint4*)&Ts[r * 80 + c16];
  *(uint4*)(dst + 8) = *(const uint4*)&Ts[r * 80 + c16 + 8];
}

// ---------------- in-place row softmax over N_=512 + bf16 copy, one wave/row ----------------
__global__ __launch_bounds__(256) void softmax_k(
    float* __restrict__ att, unsigned short* __restrict__ attb) {
  const int row  = blockIdx.x * 4 + (threadIdx.x >> 6);
  const int lane = threadIdx.x & 63;
  float* p = att + (size_t)row * N_ + lane * 8;
  float4 v0 = *(float4*)p;
  float4 v1 = *(float4*)(p + 4);
  float mx = fmaxf(fmaxf(fmaxf(v0.x, v0.y), fmaxf(v0.z, v0.w)),
                   fmaxf(fmaxf(v1.x, v1.y), fmaxf(v1.z, v1.w)));
#pragma unroll
  for (int off = 1; off < 64; off <<= 1) mx = fmaxf(mx, __shfl_xor(mx, off));
  v0.x = __expf(v0.x - mx); v0.y = __expf(v0.y - mx);
  v0.z = __expf(v0.z - mx); v0.w = __expf(v0.w - mx);
  v1.x = __expf(v1.x - mx); v1.y = __expf(v1.y - mx);
  v1.z = __expf(v1.z - mx); v1.w = __expf(v1.w - mx);
  float s = v0.x + v0.y + v0.z + v0.w + v1.x + v1.y + v1.z + v1.w;
#pragma unroll
  for (int off = 1; off < 64; off <<= 1) s += __shfl_xor(s, off);
  float inv = 1.f / s;
  v0.x *= inv; v0.y *= inv; v0.z *= inv; v0.w *= inv;
  v1.x *= inv; v1.y *= inv; v1.z *= inv; v1.w *= inv;
  *(float4*)p = v0;
  *(float4*)(p + 4) = v1;
  unsigned short* pb = attb + (size_t)row * N_ + lane * 8;
  ushort4 o0, o1;
  o0.x = f2bf(v0.x); o0.y = f2bf(v0.y); o0.z = f2bf(v0.z); o0.w = f2bf(v0.w);
  o1.x = f2bf(v1.x); o1.y = f2bf(v1.y); o1.z = f2bf(v1.z); o1.w = f2bf(v1.w);
  *(ushort4*)pb       = o0;
  *(ushort4*)(pb + 4) = o1;
}

// ---------------- y = LayerNorm(y + res) over H_=256, one wave/row ----------------
// RES_BF: residual is bf16; OUT_BF: also emit bf16 copy of result.
template<int RES_BF, int OUT_BF>
__global__ __launch_bounds__(256) void add_ln_k(
    float* __restrict__ y, const float* __restrict__ resf,
    const unsigned short* __restrict__ resb, unsigned short* __restrict__ yb) {
  const int row  = blockIdx.x * 4 + (threadIdx.x >> 6);
  const int lane = threadIdx.x & 63;
  float* py = y + (size_t)row * H_ + lane * 4;
  float4 a = *(float4*)py;
  float4 r;
  if (RES_BF) {
    ushort4 rb = *(const ushort4*)(resb + (size_t)row * H_ + lane * 4);
    r.x = bf2f(rb.x); r.y = bf2f(rb.y); r.z = bf2f(rb.z); r.w = bf2f(rb.w);
  } else {
    r = *(const float4*)(resf + (size_t)row * H_ + lane * 4);
  }
  a.x += r.x; a.y += r.y; a.z += r.z; a.w += r.w;
  float s = a.x + a.y + a.z + a.w;
#pragma unroll
  for (int off = 1; off < 64; off <<= 1) s += __shfl_xor(s, off);
  float mu = s * (1.f / H_);
  float dx = a.x - mu, dy = a.y - mu, dz = a.z - mu, dw = a.w - mu;
  float ss = dx*dx + dy*dy + dz*dz + dw*dw;
#pragma unroll
  for (int off = 1; off < 64; off <<= 1) ss += __shfl_xor(ss, off);
  float var = ss * (1.f / H_);
  float inv = 1.f / sqrtf(var + EPSF);
  float4 o;
  o.x = dx * inv; o.y = dy * inv; o.z = dz * inv; o.w = dw * inv;
  *(float4*)py = o;
  if (OUT_BF) {
    ushort4 ob;
    ob.x = f2bf(o.x); ob.y = f2bf(o.y); ob.z = f2bf(o.z); ob.w = f2bf(o.w);
    *(ushort4*)(yb + (size_t)row * H_ + lane * 4) = ob;
  }
}

extern "C" void kernel_launch(void* const* d_in, const int* in_sizes, int n_in,
                              void* d_out, int out_size, void* d_ws, size_t ws_size,
                              hipStream_t stream) {
  const float* features = (const float*)d_in[0];
  const float* masks    = (const float*)d_in[1];
  const float* guide    = (const float*)d_in[2];
  const float* prior    = (const float*)d_in[3];
  const float* WQ       = (const float*)d_in[4];
  const float* WK       = (const float*)d_in[5];
  const float* WV       = (const float*)d_in[6];
  const float* W1       = (const float*)d_in[7];
  const float* b1       = (const float*)d_in[8];
  const float* W2       = (const float*)d_in[9];
  const float* b2       = (const float*)d_in[10];

  float* out     = (float*)d_out;
  float* out_x   = out;                          // BN_*H_
  float* out_att = out + (size_t)BN_ * H_;       // 3 * B_*N_*N_

  // workspace carve-up (bytes): ~92 MB total
  char* w = (char*)d_ws;
  float* x    = (float*)w;  w += (size_t)BN_ * H_ * 4;                 // 16 MB
  float* post = (float*)w;  w += (size_t)BN_ * H_ * 4;                 // 16 MB
  unsigned short* f_bf   = (unsigned short*)w; w += (size_t)BN_ * H_ * 2;     // 8 MB
  unsigned short* q_bf   = (unsigned short*)w; w += (size_t)BN_ * H_ * 2;     // 8 MB (alias t1)
  unsigned short* k_bf   = (unsigned short*)w; w += (size_t)BN_ * H_ * 2;     // 8 MB (alias post_bf)
  unsigned short* v_bf   = (unsigned short*)w; w += (size_t)BN_ * H_ * 2;     // 8 MB
  unsigned short* vT     = (unsigned short*)w; w += (size_t)BN_ * H_ * 2;     // 8 MB
  unsigned short* att_bf = (unsigned short*)w; w += (size_t)B_ * N_ * N_ * 2; // 16 MB
  unsigned short* wq_bf  = (unsigned short*)w; w += (size_t)S_ * H_ * H_ * 2; // 384 KB
  unsigned short* wk_bf  = (unsigned short*)w; w += (size_t)S_ * H_ * H_ * 2;
  unsigned short* wv_bf  = (unsigned short*)w; w += (size_t)S_ * H_ * H_ * 2;
  unsigned short* w1_bf  = (unsigned short*)w; w += (size_t)S_ * H_ * H_ * 2;
  unsigned short* w2_bf  = (unsigned short*)w; w += (size_t)S_ * H_ * H_ * 2;
  unsigned short* t1_bf   = q_bf;   // q dead after qk_logits
  unsigned short* post_bf = k_bf;   // k dead after qk_logits

  dim3 blk(256);
  dim3 g_cvtw(S_ * H_ * H_ / 1024);            // 192
  dim3 g_ew(BN_ * H_ / 1024);                  // 4096
  dim3 g_proj(H_ / 128, BN_ / 128, 1);         // (2, 128)
  dim3 g_qk(N_ / 128, N_ / 128, B_);           // (4, 4, 32)
  dim3 g_pv(H_ / 128, N_ / 128, B_);           // (2, 4, 32)
  dim3 g_tr(H_ / 64, N_ / 64, B_);             // (4, 8, 32)
  dim3 g_row(BN_ / 4);                         // 4096
  dim3 g_att((size_t)B_ * N_ * N_ / 1024);     // 8192

  // weights -> bf16 (once per launch; cheap)
  cvt_bf16_k<<<g_cvtw, blk, 0, stream>>>(WQ, wq_bf);
  cvt_bf16_k<<<g_cvtw, blk, 0, stream>>>(WK, wk_bf);
  cvt_bf16_k<<<g_cvtw, blk, 0, stream>>>(WV, wv_bf);
  cvt_bf16_k<<<g_cvtw, blk, 0, stream>>>(W1, w1_bf);
  cvt_bf16_k<<<g_cvtw, blk, 0, stream>>>(W2, w2_bf);

  const long sQK_A = (long)N_ * H_;   // per-batch q/k stride
  const long sAtt  = (long)N_ * N_;
  const long sPost = (long)N_ * H_;

  const float* xin = features;
  for (int i = 0; i < S_; ++i) {
    mask_mul_k<1><<<g_ew, blk, 0, stream>>>(xin, masks, nullptr, f_bf);
    float* att = out_att + (size_t)i * B_ * N_ * N_;
    if (i == 0) {
      copy_cvt_k<<<g_att, blk, 0, stream>>>(prior, att, att_bf);
    } else {
      mfma_gemm_k<0><<<g_proj, blk, 0, stream>>>(f_bf, wq_bf + (size_t)i*H_*H_, nullptr, nullptr, nullptr,
                                                 nullptr, q_bf, BN_, H_, H_, 0, 0, (long)BN_*H_);
      mfma_gemm_k<0><<<g_proj, blk, 0, stream>>>(f_bf, wk_bf + (size_t)i*H_*H_, nullptr, nullptr, nullptr,
                                                 nullptr, k_bf, BN_, H_, H_, 0, 0, (long)BN_*H_);
      mfma_gemm_k<1><<<g_qk, blk, 0, stream>>>(q_bf, k_bf, nullptr, masks, guide,
                                               att, nullptr, N_, H_, N_, sQK_A, sQK_A, sAtt);
      softmax_k<<<g_row, blk, 0, stream>>>(att, att_bf);
    }
    mfma_gemm_k<0><<<g_proj, blk, 0, stream>>>(f_bf, wv_bf + (size_t)i*H_*H_, nullptr, nullptr, nullptr,
                                               nullptr, v_bf, BN_, H_, H_, 0, 0, (long)BN_*H_);
    transpose_k<<<g_tr, blk, 0, stream>>>(v_bf, vT);
    // post_raw = att @ v  (A = att bf16 [m][k], B = vT bf16 [n][k])
    mfma_gemm_k<2><<<g_pv, blk, 0, stream>>>(att_bf, vT, nullptr, nullptr, nullptr,
                                             post, nullptr, N_, N_, H_, sAtt, sPost, sPost);
    // post = LN(post_raw + f)
    add_ln_k<1, 1><<<g_row, blk, 0, stream>>>(post, nullptr, f_bf, post_bf);
    // t1 = relu(post @ W1^T + b1)  -> bf16
    mfma_gemm_k<3><<<g_proj, blk, 0, stream>>>(post_bf, w1_bf + (size_t)i*H_*H_, b1 + (size_t)i*H_,
                                               nullptr, nullptr, nullptr, t1_bf,
                                               BN_, H_, H_, 0, 0, (long)BN_*H_);
    // x = t1 @ W2^T + b2  -> fp32
    mfma_gemm_k<4><<<g_proj, blk, 0, stream>>>(t1_bf, w2_bf + (size_t)i*H_*H_, b2 + (size_t)i*H_,
                                               nullptr, nullptr, x, nullptr,
                                               BN_, H_, H_, 0, 0, (long)BN_*H_);
    // x = LN(x + post)
    add_ln_k<0, 0><<<g_row, blk, 0, stream>>>(x, post, nullptr, nullptr);
    xin = x;
  }
  mask_mul_k<0><<<g_ew, blk, 0, stream>>>(x, masks, out_x, nullptr);
}

// Round 3
// 527.025 us; speedup vs baseline: 2.0830x; 1.0424x over previous
//
#include <hip/hip_runtime.h>
#include <cstdint>
#include <cstddef>

#define B_ 32
#define N_ 512
#define H_ 256
#define S_ 3
#define BN_ (B_*N_)            // 16384
#define HH_ (H_*H_)            // 65536
#define BIGF 3.4028234e+38f
#define EPSF 1e-5f

typedef __bf16 bf16x8 __attribute__((ext_vector_type(8)));
typedef float  f32x4  __attribute__((ext_vector_type(4)));

__device__ __forceinline__ unsigned short f2bf(float f) {
  __bf16 h = (__bf16)f;             // RNE convert
  unsigned short s;
  __builtin_memcpy(&s, &h, 2);
  return s;
}
__device__ __forceinline__ float bf2f(unsigned short u) {
  unsigned int v = ((unsigned int)u) << 16;
  float f;
  __builtin_memcpy(&f, &v, 4);
  return f;
}

// ------------- all 5 weight tensors -> bf16 in one dispatch -------------
// WQ,WK interleave into wqk[layer][512][256] (rows 0..255 = WQ[l], 256..511 = WK[l]).
__global__ __launch_bounds__(256) void cvt_all_k(
    const float* __restrict__ WQ, const float* __restrict__ WK,
    const float* __restrict__ WV, const float* __restrict__ W1,
    const float* __restrict__ W2,
    unsigned short* __restrict__ wqk, unsigned short* __restrict__ wv,
    unsigned short* __restrict__ w1, unsigned short* __restrict__ w2) {
  const int per = S_ * HH_ / 4;                   // float4 per tensor
  int gi = blockIdx.x * 256 + threadIdx.x;
  int which = gi / per;
  int e4 = gi - which * per;
  float4 v;
  if      (which == 0) v = ((const float4*)WQ)[e4];
  else if (which == 1) v = ((const float4*)WK)[e4];
  else if (which == 2) v = ((const float4*)WV)[e4];
  else if (which == 3) v = ((const float4*)W1)[e4];
  else                 v = ((const float4*)W2)[e4];
  ushort4 o;
  o.x = f2bf(v.x); o.y = f2bf(v.y); o.z = f2bf(v.z); o.w = f2bf(v.w);
  int e = e4 * 4;
  if (which <= 1) {
    int L = e / HH_, off = e - L * HH_;
    *(ushort4*)&wqk[(size_t)L * 2 * HH_ + (which == 1 ? HH_ : 0) + off] = o;
  } else if (which == 2) ((ushort4*)wv)[e4] = o;
  else if   (which == 3) ((ushort4*)w1)[e4] = o;
  else                   ((ushort4*)w2)[e4] = o;
}

// ------------- f_bf = bf16(x * mask_row) (layer-0 only) -------------
__global__ __launch_bounds__(256) void mask_mul_k(
    const float* __restrict__ x, const float* __restrict__ masks,
    unsigned short* __restrict__ fb) {
  int i = blockIdx.x * 256 + threadIdx.x;   // float4 index; 64 per row
  int row = i >> 6;
  float m = masks[row];
  float4 v = ((const float4*)x)[i];
  ushort4 o;
  o.x = f2bf(v.x * m); o.y = f2bf(v.y * m); o.z = f2bf(v.z * m); o.w = f2bf(v.w * m);
  ((ushort4*)fb)[i] = o;
}

// ------------- prior -> att fp32 + att bf16 -------------
__global__ __launch_bounds__(256) void copy_cvt_k(
    const float* __restrict__ src, float* __restrict__ dstf,
    unsigned short* __restrict__ dstb) {
  int i = blockIdx.x * 256 + threadIdx.x;
  float4 v = ((const float4*)src)[i];
  ((float4*)dstf)[i] = v;
  ushort4 o;
  o.x = f2bf(v.x); o.y = f2bf(v.y); o.z = f2bf(v.z); o.w = f2bf(v.w);
  ((ushort4*)dstb)[i] = o;
}

// ================= MFMA GEMM: C = A(bf16,[m][k],lda) @ B(bf16,[n][k],ldb)^T =================
// 128x128 tile, BK=32, 256 threads (4 waves 2x2), 4x4 grid of 16x16x32 mfma per wave.
// EPI: 0 = bf16 out; 1 = qk logits (scale/mask/guide, fp32 out); 3 = bias+relu -> bf16.
template<int EPI>
__global__ __launch_bounds__(256) void mfma_gemm_k(
    const unsigned short* __restrict__ A, const unsigned short* __restrict__ Bm,
    const float* __restrict__ bias, const float* __restrict__ masks,
    const float* __restrict__ guide,
    float* __restrict__ Cf, unsigned short* __restrict__ Cb,
    int K, int Nn, int lda, int ldb, long sA, long sB, long sC) {
  __shared__ __align__(16) unsigned short As[128 * 40];
  __shared__ __align__(16) unsigned short Bs[128 * 40];
  const int b = blockIdx.z;
  const unsigned short* Ap = A + (size_t)b * sA;
  const unsigned short* Bp = Bm + (size_t)b * sB;
  const int t = threadIdx.x;
  const int wave = t >> 6, lane = t & 63;
  const int wm = wave >> 1, wn = wave & 1;
  const int quad = lane >> 4, l15 = lane & 15;
  const int m0 = blockIdx.y * 128, n0 = blockIdx.x * 128;
  const int srow = t >> 1, soff = (t & 1) * 16;

  f32x4 acc[4][4];
#pragma unroll
  for (int i = 0; i < 4; ++i)
#pragma unroll
    for (int j = 0; j < 4; ++j) acc[i][j] = (f32x4){0.f, 0.f, 0.f, 0.f};

  const unsigned short* pa = Ap + (size_t)(m0 + srow) * lda + soff;
  const unsigned short* pb = Bp + (size_t)(n0 + srow) * ldb + soff;
  unsigned short* wsa = &As[srow * 40 + soff];
  unsigned short* wsb = &Bs[srow * 40 + soff];

  for (int k0 = 0; k0 < K; k0 += 32) {
    uint4 a0 = *(const uint4*)(pa + k0);
    uint4 a1 = *(const uint4*)(pa + k0 + 8);
    uint4 b0 = *(const uint4*)(pb + k0);
    uint4 b1 = *(const uint4*)(pb + k0 + 8);
    __syncthreads();
    *(uint4*)wsa = a0; *(uint4*)(wsa + 8) = a1;
    *(uint4*)wsb = b0; *(uint4*)(wsb + 8) = b1;
    __syncthreads();
    bf16x8 af[4], bfr[4];
#pragma unroll
    for (int i = 0; i < 4; ++i)
      af[i] = *(const bf16x8*)&As[(wm * 64 + i * 16 + l15) * 40 + quad * 8];
#pragma unroll
    for (int j = 0; j < 4; ++j)
      bfr[j] = *(const bf16x8*)&Bs[(wn * 64 + j * 16 + l15) * 40 + quad * 8];
#pragma unroll
    for (int i = 0; i < 4; ++i)
#pragma unroll
      for (int j = 0; j < 4; ++j)
        acc[i][j] = __builtin_amdgcn_mfma_f32_16x16x32_bf16(af[i], bfr[j], acc[i][j], 0, 0, 0);
  }

  float bv[4];
  if (EPI == 3) {
#pragma unroll
    for (int j = 0; j < 4; ++j) bv[j] = bias[n0 + wn * 64 + j * 16 + l15];
  }
  float am[4];
  if (EPI == 1) {
#pragma unroll
    for (int j = 0; j < 4; ++j) {
      float mv = masks[(size_t)b * N_ + n0 + wn * 64 + j * 16 + l15];
      am[j] = (mv != 0.f) ? 0.f : BIGF;
    }
  }
#pragma unroll
  for (int i = 0; i < 4; ++i) {
    const int rbase = m0 + wm * 64 + i * 16 + quad * 4;
#pragma unroll
    for (int j = 0; j < 4; ++j) {
      const int c = n0 + wn * 64 + j * 16 + l15;
#pragma unroll
      for (int r = 0; r < 4; ++r) {
        const int m = rbase + r;
        float val = acc[i][j][r];
        if (EPI == 1) {
          float g = guide[((size_t)b * N_ + m) * N_ + c];
          val = val * 0.0625f - am[j] - ((g != 0.f) ? 0.f : BIGF);
          Cf[(size_t)b * sC + (size_t)m * Nn + c] = val;
        } else if (EPI == 3) {
          Cb[(size_t)b * sC + (size_t)m * Nn + c] = f2bf(fmaxf(val + bv[j], 0.f));
        } else {
          Cb[(size_t)b * sC + (size_t)m * Nn + c] = f2bf(val);
        }
      }
    }
  }
}

// ========== MFMA GEMM (64x256 tile, full H row) + add-residual + LayerNorm ==========
// 256 threads = 4 waves 1x4 (wave w -> cols w*64..w*64+63). Nn == H_ == 256 fixed.
// EPI: 0 = PV-LN:   residual bf16 (f_bf),  out post fp32 + post_bf bf16
//      1 = FFN2-LN: +bias, residual fp32 (post), out f_bf = bf16(mask * LN)
//      2 = FFN2-LN last: +bias, residual fp32,   out fp32 = mask * LN
template<int EPI>
__global__ __launch_bounds__(256) void gemm_ln_k(
    const unsigned short* __restrict__ A, const unsigned short* __restrict__ Bm,
    const float* __restrict__ bias, const float* __restrict__ masks,
    const unsigned short* __restrict__ resb, const float* __restrict__ resf,
    float* __restrict__ outf, unsigned short* __restrict__ outb,
    int K, long sA, long sB) {
  __shared__ __align__(16) unsigned short As[64 * 40];
  __shared__ __align__(16) unsigned short Bs[256 * 40];
  __shared__ float red[4][64][2];
  const int b = blockIdx.z;
  const int t = threadIdx.x;
  const int wvi = t >> 6, lane = t & 63;
  const int quad = lane >> 4, l15 = lane & 15;
  const int m0 = blockIdx.y * 64;
  const unsigned short* Ap = A + (size_t)b * sA + (size_t)m0 * K;
  const unsigned short* Bp = Bm + (size_t)b * sB;
  const int arow = t >> 2, aoff = (t & 3) * 8;
  const unsigned short* pa = Ap + (size_t)arow * K + aoff;
  const unsigned short* pb = Bp + (size_t)t * K;

  f32x4 acc[4][4];
#pragma unroll
  for (int i = 0; i < 4; ++i)
#pragma unroll
    for (int j = 0; j < 4; ++j) acc[i][j] = (f32x4){0.f, 0.f, 0.f, 0.f};

  for (int k0 = 0; k0 < K; k0 += 32) {
    uint4 av = *(const uint4*)(pa + k0);
    uint4 b0 = *(const uint4*)(pb + k0);
    uint4 b1 = *(const uint4*)(pb + k0 + 8);
    uint4 b2 = *(const uint4*)(pb + k0 + 16);
    uint4 b3 = *(const uint4*)(pb + k0 + 24);
    __syncthreads();
    *(uint4*)&As[arow * 40 + aoff] = av;
    unsigned short* bw = &Bs[t * 40];
    *(uint4*)(bw + 0) = b0; *(uint4*)(bw + 8)  = b1;
    *(uint4*)(bw + 16) = b2; *(uint4*)(bw + 24) = b3;
    __syncthreads();
    bf16x8 af[4], bfr[4];
#pragma unroll
    for (int i = 0; i < 4; ++i)
      af[i] = *(const bf16x8*)&As[(i * 16 + l15) * 40 + quad * 8];
#pragma unroll
    for (int j = 0; j < 4; ++j)
      bfr[j] = *(const bf16x8*)&Bs[(wvi * 64 + j * 16 + l15) * 40 + quad * 8];
#pragma unroll
    for (int i = 0; i < 4; ++i)
#pragma unroll
      for (int j = 0; j < 4; ++j)
        acc[i][j] = __builtin_amdgcn_mfma_f32_16x16x32_bf16(af[i], bfr[j], acc[i][j], 0, 0, 0);
  }

  float bv[4];
  if (EPI >= 1) {
#pragma unroll
    for (int j = 0; j < 4; ++j) bv[j] = bias[wvi * 64 + j * 16 + l15];
  }
  // bias + residual, per-row partial sum/sumsq, cross-lane then cross-wave reduce
#pragma unroll
  for (int i = 0; i < 4; ++i) {
#pragma unroll
    for (int r = 0; r < 4; ++r) {
      const int mloc = i * 16 + quad * 4 + r;
      const long grow = (long)b * N_ + m0 + mloc;
      float s = 0.f, q = 0.f;
#pragma unroll
      for (int j = 0; j < 4; ++j) {
        const int c = wvi * 64 + j * 16 + l15;
        float v = acc[i][j][r];
        if (EPI >= 1) v += bv[j];
        v += (EPI == 0) ? bf2f(resb[grow * H_ + c]) : resf[grow * H_ + c];
        acc[i][j][r] = v;
        s += v; q += v * v;
      }
#pragma unroll
      for (int off = 1; off < 16; off <<= 1) {
        s += __shfl_xor(s, off);
        q += __shfl_xor(q, off);
      }
      if (l15 == 0) { red[wvi][mloc][0] = s; red[wvi][mloc][1] = q; }
    }
  }
  __syncthreads();
#pragma unroll
  for (int i = 0; i < 4; ++i) {
#pragma unroll
    for (int r = 0; r < 4; ++r) {
      const int mloc = i * 16 + quad * 4 + r;
      const long grow = (long)b * N_ + m0 + mloc;
      float S = red[0][mloc][0] + red[1][mloc][0] + red[2][mloc][0] + red[3][mloc][0];
      float Q = red[0][mloc][1] + red[1][mloc][1] + red[2][mloc][1] + red[3][mloc][1];
      float mu = S * (1.f / H_);
      float var = Q * (1.f / H_) - mu * mu;
      float inv = 1.f / sqrtf(var + EPSF);
      float mval = (EPI >= 1) ? masks[grow] : 0.f;
#pragma unroll
      for (int j = 0; j < 4; ++j) {
        const int c = wvi * 64 + j * 16 + l15;
        float o = (acc[i][j][r] - mu) * inv;
        if (EPI == 0) {
          outf[grow * H_ + c] = o;
          outb[grow * H_ + c] = f2bf(o);
        } else if (EPI == 1) {
          outb[grow * H_ + c] = f2bf(o * mval);
        } else {
          outf[grow * H_ + c] = o * mval;
        }
      }
    }
  }
}

// ------------- in-place row softmax over N_=512 + bf16 copy, one wave/row -------------
__global__ __launch_bounds__(256) void softmax_k(
    float* __restrict__ att, unsigned short* __restrict__ attb) {
  const int row  = blockIdx.x * 4 + (threadIdx.x >> 6);
  const int lane = threadIdx.x & 63;
  float* p = att + (size_t)row * N_ + lane * 8;
  float4 v0 = *(float4*)p;
  float4 v1 = *(float4*)(p + 4);
  float mx = fmaxf(fmaxf(fmaxf(v0.x, v0.y), fmaxf(v0.z, v0.w)),
                   fmaxf(fmaxf(v1.x, v1.y), fmaxf(v1.z, v1.w)));
#pragma unroll
  for (int off = 1; off < 64; off <<= 1) mx = fmaxf(mx, __shfl_xor(mx, off));
  v0.x = __expf(v0.x - mx); v0.y = __expf(v0.y - mx);
  v0.z = __expf(v0.z - mx); v0.w = __expf(v0.w - mx);
  v1.x = __expf(v1.x - mx); v1.y = __expf(v1.y - mx);
  v1.z = __expf(v1.z - mx); v1.w = __expf(v1.w - mx);
  float s = v0.x + v0.y + v0.z + v0.w + v1.x + v1.y + v1.z + v1.w;
#pragma unroll
  for (int off = 1; off < 64; off <<= 1) s += __shfl_xor(s, off);
  float inv = 1.f / s;
  v0.x *= inv; v0.y *= inv; v0.z *= inv; v0.w *= inv;
  v1.x *= inv; v1.y *= inv; v1.z *= inv; v1.w *= inv;
  *(float4*)p = v0;
  *(float4*)(p + 4) = v1;
  unsigned short* pb = attb + (size_t)row * N_ + lane * 8;
  ushort4 o0, o1;
  o0.x = f2bf(v0.x); o0.y = f2bf(v0.y); o0.z = f2bf(v0.z); o0.w = f2bf(v0.w);
  o1.x = f2bf(v1.x); o1.y = f2bf(v1.y); o1.z = f2bf(v1.z); o1.w = f2bf(v1.w);
  *(ushort4*)pb       = o0;
  *(ushort4*)(pb + 4) = o1;
}

extern "C" void kernel_launch(void* const* d_in, const int* in_sizes, int n_in,
                              void* d_out, int out_size, void* d_ws, size_t ws_size,
                              hipStream_t stream) {
  const float* features = (const float*)d_in[0];
  const float* masks    = (const float*)d_in[1];
  const float* guide    = (const float*)d_in[2];
  const float* prior    = (const float*)d_in[3];
  const float* WQ       = (const float*)d_in[4];
  const float* WK       = (const float*)d_in[5];
  const float* WV       = (const float*)d_in[6];
  const float* W1       = (const float*)d_in[7];
  const float* b1       = (const float*)d_in[8];
  const float* W2       = (const float*)d_in[9];
  const float* b2       = (const float*)d_in[10];

  float* out     = (float*)d_out;
  float* out_x   = out;
  float* out_att = out + (size_t)BN_ * H_;

  // workspace carve-up: ~74 MB
  char* w = (char*)d_ws;
  float* post = (float*)w;                     w += (size_t)BN_ * H_ * 4;        // 16 MB
  unsigned short* f_bf   = (unsigned short*)w; w += (size_t)BN_ * H_ * 2;        // 8 MB
  unsigned short* qk_bf  = (unsigned short*)w; w += (size_t)BN_ * 2 * H_ * 2;    // 16 MB
  unsigned short* post_bf= (unsigned short*)w; w += (size_t)BN_ * H_ * 2;        // 8 MB
  unsigned short* vT     = (unsigned short*)w; w += (size_t)BN_ * H_ * 2;        // 8 MB
  unsigned short* att_bf = (unsigned short*)w; w += (size_t)B_ * N_ * N_ * 2;    // 16 MB
  unsigned short* wqk_bf = (unsigned short*)w; w += (size_t)S_ * 2 * HH_ * 2;    // 768 KB
  unsigned short* wv_bf  = (unsigned short*)w; w += (size_t)S_ * HH_ * 2;        // 384 KB
  unsigned short* w1_bf  = (unsigned short*)w; w += (size_t)S_ * HH_ * 2;
  unsigned short* w2_bf  = (unsigned short*)w; w += (size_t)S_ * HH_ * 2;
  unsigned short* t1_bf  = qk_bf;   // qk dead after logits; t1 dead before next qk write

  dim3 blk(256);
  dim3 g_cvt(5 * S_ * HH_ / 1024);             // 960
  dim3 g_ew(BN_ * H_ / 1024);                  // 4096
  dim3 g_att((size_t)B_ * N_ * N_ / 1024);     // 8192
  dim3 g_qkp(4, BN_ / 128, 1);                 // QK fused proj: Nn=512
  dim3 g_lg(4, 4, B_);                         // logits 512x512 per batch
  dim3 g_vt(4, 2, B_);                         // vT: Nn=512, M=256
  dim3 g_f1(2, BN_ / 128, 1);                  // FFN1: Nn=256
  dim3 g_pv(1, N_ / 64, B_);                   // PV-LN: 64-row blocks per batch
  dim3 g_f2(1, BN_ / 64, 1);                   // FFN2-LN
  dim3 g_row(BN_ / 4);                         // softmax

  cvt_all_k<<<g_cvt, blk, 0, stream>>>(WQ, WK, WV, W1, W2, wqk_bf, wv_bf, w1_bf, w2_bf);
  mask_mul_k<<<g_ew, blk, 0, stream>>>(features, masks, f_bf);

  const long sLG = (long)N_ * N_;      // att per-batch stride
  const long sQK = (long)N_ * 2 * H_;  // qk per-batch stride (rows of 512)
  const long sF  = (long)N_ * H_;      // f per-batch stride
  const long sVT = (long)H_ * N_;      // vT per-batch stride

  for (int i = 0; i < S_; ++i) {
    float* att = out_att + (size_t)i * B_ * N_ * N_;
    if (i == 0) {
      copy_cvt_k<<<g_att, blk, 0, stream>>>(prior, att, att_bf);
    } else {
      // qk = f @ [WQ;WK]^T  -> bf16 [BN][512]
      mfma_gemm_k<0><<<g_qkp, blk, 0, stream>>>(f_bf, wqk_bf + (size_t)i * 2 * HH_,
          nullptr, nullptr, nullptr, nullptr, qk_bf,
          H_, 2 * H_, H_, H_, 0, 0, 0);
      // logits = q @ k^T * scale - masks - guide_inf  -> att fp32
      mfma_gemm_k<1><<<g_lg, blk, 0, stream>>>(qk_bf, qk_bf + H_,
          nullptr, masks, guide, att, nullptr,
          H_, N_, 2 * H_, 2 * H_, sQK, sQK, sLG);
      softmax_k<<<g_row, blk, 0, stream>>>(att, att_bf);
    }
    // vT[b][h][n] = WV[i] @ f[b]^T  -> bf16 [B][H][N]
    mfma_gemm_k<0><<<g_vt, blk, 0, stream>>>(wv_bf + (size_t)i * HH_, f_bf,
        nullptr, nullptr, nullptr, nullptr, vT,
        H_, N_, H_, H_, 0, sF, sVT);
    // post = LN(att @ v + f)  -> fp32 + bf16
    gemm_ln_k<0><<<g_pv, blk, 0, stream>>>(att_bf, vT, nullptr, nullptr,
        f_bf, nullptr, post, post_bf, N_, sLG, sVT);
    // t1 = relu(post @ W1^T + b1) -> bf16
    mfma_gemm_k<3><<<g_f1, blk, 0, stream>>>(post_bf, w1_bf + (size_t)i * HH_,
        b1 + (size_t)i * H_, nullptr, nullptr, nullptr, t1_bf,
        H_, H_, H_, H_, 0, 0, 0);
    // x = LN(t1 @ W2^T + b2 + post); emit f_bf = bf16(mask*x) (i<2) or out_x = mask*x (i==2)
    if (i < S_ - 1) {
      gemm_ln_k<1><<<g_f2, blk, 0, stream>>>(t1_bf, w2_bf + (size_t)i * HH_,
          b2 + (size_t)i * H_, masks, nullptr, post, nullptr, f_bf, H_, 0, 0);
    } else {
      gemm_ln_k<2><<<g_f2, blk, 0, stream>>>(t1_bf, w2_bf + (size_t)i * HH_,
          b2 + (size_t)i * H_, masks, nullptr, post, out_x, nullptr, H_, 0, 0);
    }
  }
}

// Round 4
// 449.182 us; speedup vs baseline: 2.4440x; 1.1733x over previous
//
#include <hip/hip_runtime.h>
#include <cstdint>
#include <cstddef>

#define B_ 32
#define N_ 512
#define H_ 256
#define S_ 3
#define BN_ (B_*N_)            // 16384
#define HH_ (H_*H_)            // 65536
#define BIGF 3.4028234e+38f
#define EPSF 1e-5f

typedef __bf16 bf16x8 __attribute__((ext_vector_type(8)));
typedef float  f32x4  __attribute__((ext_vector_type(4)));

typedef const void __attribute__((address_space(1)))* gas_t;
typedef void __attribute__((address_space(3)))* las_t;

// async global->LDS, 16B per lane. LDS dest is wave-uniform base + lane*16.
__device__ __forceinline__ void async16(const unsigned short* g, unsigned short* l) {
  __builtin_amdgcn_global_load_lds((gas_t)g, (las_t)l, 16, 0, 0);
}

__device__ __forceinline__ unsigned short f2bf(float f) {
  __bf16 h = (__bf16)f;
  unsigned short s;
  __builtin_memcpy(&s, &h, 2);
  return s;
}
__device__ __forceinline__ float bf2f(unsigned short u) {
  unsigned int v = ((unsigned int)u) << 16;
  float f;
  __builtin_memcpy(&f, &v, 4);
  return f;
}

// ------------- all 5 weight tensors -> bf16 in one dispatch -------------
__global__ __launch_bounds__(256) void cvt_all_k(
    const float* __restrict__ WQ, const float* __restrict__ WK,
    const float* __restrict__ WV, const float* __restrict__ W1,
    const float* __restrict__ W2,
    unsigned short* __restrict__ wqk, unsigned short* __restrict__ wv,
    unsigned short* __restrict__ w1, unsigned short* __restrict__ w2) {
  const int per = S_ * HH_ / 4;
  int gi = blockIdx.x * 256 + threadIdx.x;
  int which = gi / per;
  int e4 = gi - which * per;
  float4 v;
  if      (which == 0) v = ((const float4*)WQ)[e4];
  else if (which == 1) v = ((const float4*)WK)[e4];
  else if (which == 2) v = ((const float4*)WV)[e4];
  else if (which == 3) v = ((const float4*)W1)[e4];
  else                 v = ((const float4*)W2)[e4];
  ushort4 o;
  o.x = f2bf(v.x); o.y = f2bf(v.y); o.z = f2bf(v.z); o.w = f2bf(v.w);
  int e = e4 * 4;
  if (which <= 1) {
    int L = e / HH_, off = e - L * HH_;
    *(ushort4*)&wqk[(size_t)L * 2 * HH_ + (which == 1 ? HH_ : 0) + off] = o;
  } else if (which == 2) ((ushort4*)wv)[e4] = o;
  else if   (which == 3) ((ushort4*)w1)[e4] = o;
  else                   ((ushort4*)w2)[e4] = o;
}

// ------------- f_bf = bf16(x * mask_row) -------------
__global__ __launch_bounds__(256) void mask_mul_k(
    const float* __restrict__ x, const float* __restrict__ masks,
    unsigned short* __restrict__ fb) {
  int i = blockIdx.x * 256 + threadIdx.x;
  int row = i >> 6;
  float m = masks[row];
  float4 v = ((const float4*)x)[i];
  ushort4 o;
  o.x = f2bf(v.x * m); o.y = f2bf(v.y * m); o.z = f2bf(v.z * m); o.w = f2bf(v.w * m);
  ((ushort4*)fb)[i] = o;
}

// ------------- prior -> att fp32 + att bf16 -------------
__global__ __launch_bounds__(256) void copy_cvt_k(
    const float* __restrict__ src, float* __restrict__ dstf,
    unsigned short* __restrict__ dstb) {
  int i = blockIdx.x * 256 + threadIdx.x;
  float4 v = ((const float4*)src)[i];
  ((float4*)dstf)[i] = v;
  ushort4 o;
  o.x = f2bf(v.x); o.y = f2bf(v.y); o.z = f2bf(v.z); o.w = f2bf(v.w);
  ((ushort4*)dstb)[i] = o;
}

// XOR-swizzle helpers: LDS rows are 32 shorts (64B), 4 chunks of 8 shorts.
// Stage: lane writes LDS chunk (lane&3) of row (lane>>2); it fetches global
// k-chunk ((lane&3) ^ ((lane>>3)&3)). Read: k-quad `quad` of row ri lives at
// chunk (quad ^ ((ri>>1)&3)); row bases are multiples of 16 so only l15 matters.
#define KC_STAGE(lane) ((((lane) & 3) ^ (((lane) >> 3) & 3)) * 8)
#define KC_READ(quad, l15) ((((quad) ^ (((l15) >> 1) & 3))) * 8)

// ================= MFMA GEMM (128x128, BK=32, async staging) =================
// C = A(bf16,[m][k],lda) @ B(bf16,[n][k],ldb)^T. EPI: 0 = bf16 out; 3 = bias+relu bf16.
template<int EPI>
__global__ __launch_bounds__(256) void mfma_gemm_k(
    const unsigned short* __restrict__ A, const unsigned short* __restrict__ Bm,
    const float* __restrict__ bias, unsigned short* __restrict__ Cb,
    int K, int Nn, int lda, int ldb, long sA, long sB, long sC) {
  __shared__ __align__(16) unsigned short As[128 * 32];
  __shared__ __align__(16) unsigned short Bs[128 * 32];
  const int b = blockIdx.z;
  const int t = threadIdx.x;
  const int wave = t >> 6, lane = t & 63;
  const int wm = wave >> 1, wn = wave & 1;
  const int quad = lane >> 4, l15 = lane & 15;
  const int m0 = blockIdx.y * 128, n0 = blockIdx.x * 128;
  const int srow = lane >> 2;
  const int kc = KC_STAGE(lane);
  const int pos8 = (lane & 3) * 8;

  const unsigned short* pa0 = A + (size_t)b * sA + (size_t)(m0 + wave * 32 + srow) * lda + kc;
  const unsigned short* pa1 = pa0 + 16 * (size_t)lda;
  const unsigned short* pb0 = Bm + (size_t)b * sB + (size_t)(n0 + wave * 32 + srow) * ldb + kc;
  const unsigned short* pb1 = pb0 + 16 * (size_t)ldb;
  unsigned short* la0 = &As[(wave * 32 + srow) * 32 + pos8];
  unsigned short* la1 = la0 + 16 * 32;
  unsigned short* lb0 = &Bs[(wave * 32 + srow) * 32 + pos8];
  unsigned short* lb1 = lb0 + 16 * 32;

  f32x4 acc[4][4];
#pragma unroll
  for (int i = 0; i < 4; ++i)
#pragma unroll
    for (int j = 0; j < 4; ++j) acc[i][j] = (f32x4){0.f, 0.f, 0.f, 0.f};

  const int soff = KC_READ(quad, l15);
  for (int k0 = 0; k0 < K; k0 += 32) {
    async16(pa0 + k0, la0); async16(pa1 + k0, la1);
    async16(pb0 + k0, lb0); async16(pb1 + k0, lb1);
    __syncthreads();
    bf16x8 af[4], bfr[4];
#pragma unroll
    for (int i = 0; i < 4; ++i)
      af[i] = *(const bf16x8*)&As[(wm * 64 + i * 16 + l15) * 32 + soff];
#pragma unroll
    for (int j = 0; j < 4; ++j)
      bfr[j] = *(const bf16x8*)&Bs[(wn * 64 + j * 16 + l15) * 32 + soff];
#pragma unroll
    for (int i = 0; i < 4; ++i)
#pragma unroll
      for (int j = 0; j < 4; ++j)
        acc[i][j] = __builtin_amdgcn_mfma_f32_16x16x32_bf16(af[i], bfr[j], acc[i][j], 0, 0, 0);
    __syncthreads();
  }

  float bv[4];
  if (EPI == 3) {
#pragma unroll
    for (int j = 0; j < 4; ++j) bv[j] = bias[n0 + wn * 64 + j * 16 + l15];
  }
#pragma unroll
  for (int i = 0; i < 4; ++i) {
    const int rbase = m0 + wm * 64 + i * 16 + quad * 4;
#pragma unroll
    for (int j = 0; j < 4; ++j) {
      const int c = n0 + wn * 64 + j * 16 + l15;
#pragma unroll
      for (int r = 0; r < 4; ++r) {
        const int m = rbase + r;
        float val = acc[i][j][r];
        if (EPI == 3) val = fmaxf(val + bv[j], 0.f);
        Cb[(size_t)b * sC + (size_t)m * Nn + c] = f2bf(val);
      }
    }
  }
}

// ========== Fused QK^T + mask/guide + softmax, 64x512 row-tile, 512 threads ==========
// qk layout: [b][n][512] with cols 0..255 = q, 256..511 = k. Wave grid 2x4:
// wm = wave>>2 (rows wm*32), wn = wave&3 (cols wn*128).
__global__ __launch_bounds__(512) void ls_k(
    const unsigned short* __restrict__ qk, const float* __restrict__ masks,
    const float* __restrict__ guide,
    float* __restrict__ att, unsigned short* __restrict__ attb) {
  __shared__ __align__(16) unsigned short As[64 * 32];
  __shared__ __align__(16) unsigned short Bs[512 * 32];
  __shared__ float red[4][64][2];
  const int b = blockIdx.z;
  const int t = threadIdx.x;
  const int wave = t >> 6, lane = t & 63;
  const int wm = wave >> 2, wn = wave & 3;
  const int quad = lane >> 4, l15 = lane & 15;
  const int m0 = blockIdx.y * 64;
  const int srow = lane >> 2;
  const int kc = KC_STAGE(lane);
  const int pos8 = (lane & 3) * 8;
  const int ld = 2 * H_;

  const unsigned short* base = qk + (size_t)b * N_ * ld;
  const unsigned short* pa = base + (size_t)(m0 + wave * 16 + srow) * ld + kc;   // waves 0..3
  unsigned short* la = &As[(wave * 16 + srow) * 32 + pos8];
  const unsigned short* pb = base + H_ + (size_t)(wave * 64 + srow) * ld + kc;   // + c*16 rows
  unsigned short* lb = &Bs[(wave * 64 + srow) * 32 + pos8];

  f32x4 acc[2][8];
#pragma unroll
  for (int i = 0; i < 2; ++i)
#pragma unroll
    for (int j = 0; j < 8; ++j) acc[i][j] = (f32x4){0.f, 0.f, 0.f, 0.f};

  const int soff = KC_READ(quad, l15);
  for (int k0 = 0; k0 < H_; k0 += 32) {
    if (wave < 4) async16(pa + k0, la);
#pragma unroll
    for (int c = 0; c < 4; ++c)
      async16(pb + (size_t)c * 16 * ld + k0, lb + c * 16 * 32);
    __syncthreads();
    bf16x8 af[2], bfr[8];
#pragma unroll
    for (int i = 0; i < 2; ++i)
      af[i] = *(const bf16x8*)&As[(wm * 32 + i * 16 + l15) * 32 + soff];
#pragma unroll
    for (int j = 0; j < 8; ++j)
      bfr[j] = *(const bf16x8*)&Bs[(wn * 128 + j * 16 + l15) * 32 + soff];
#pragma unroll
    for (int i = 0; i < 2; ++i)
#pragma unroll
      for (int j = 0; j < 8; ++j)
        acc[i][j] = __builtin_amdgcn_mfma_f32_16x16x32_bf16(af[i], bfr[j], acc[i][j], 0, 0, 0);
    __syncthreads();
  }

  // logits + row-max
  float am[8];
#pragma unroll
  for (int j = 0; j < 8; ++j) {
    float mv = masks[(size_t)b * N_ + wn * 128 + j * 16 + l15];
    am[j] = (mv != 0.f) ? 0.f : BIGF;
  }
#pragma unroll
  for (int i = 0; i < 2; ++i) {
#pragma unroll
    for (int r = 0; r < 4; ++r) {
      const int mloc = wm * 32 + i * 16 + quad * 4 + r;
      const float* gr = guide + ((size_t)b * N_ + m0 + mloc) * N_;
      float mx = -BIGF;
#pragma unroll
      for (int j = 0; j < 8; ++j) {
        const int c = wn * 128 + j * 16 + l15;
        float g = gr[c];
        float v = acc[i][j][r] * 0.0625f - am[j] - ((g != 0.f) ? 0.f : BIGF);
        acc[i][j][r] = v;
        mx = fmaxf(mx, v);
      }
#pragma unroll
      for (int off = 1; off < 16; off <<= 1) mx = fmaxf(mx, __shfl_xor(mx, off));
      if (l15 == 0) red[wn][mloc][0] = mx;
    }
  }
  __syncthreads();
  // exp + row-sum
#pragma unroll
  for (int i = 0; i < 2; ++i) {
#pragma unroll
    for (int r = 0; r < 4; ++r) {
      const int mloc = wm * 32 + i * 16 + quad * 4 + r;
      float M = fmaxf(fmaxf(red[0][mloc][0], red[1][mloc][0]),
                      fmaxf(red[2][mloc][0], red[3][mloc][0]));
      float s = 0.f;
#pragma unroll
      for (int j = 0; j < 8; ++j) {
        float e = __expf(acc[i][j][r] - M);
        acc[i][j][r] = e;
        s += e;
      }
#pragma unroll
      for (int off = 1; off < 16; off <<= 1) s += __shfl_xor(s, off);
      if (l15 == 0) red[wn][mloc][1] = s;
    }
  }
  __syncthreads();
  // normalize + store fp32 + bf16
#pragma unroll
  for (int i = 0; i < 2; ++i) {
#pragma unroll
    for (int r = 0; r < 4; ++r) {
      const int mloc = wm * 32 + i * 16 + quad * 4 + r;
      float S = red[0][mloc][1] + red[1][mloc][1] + red[2][mloc][1] + red[3][mloc][1];
      float inv = 1.f / S;
      const size_t rowoff = ((size_t)b * N_ + m0 + mloc) * N_;
#pragma unroll
      for (int j = 0; j < 8; ++j) {
        const int c = wn * 128 + j * 16 + l15;
        float o = acc[i][j][r] * inv;
        att[rowoff + c] = o;
        attb[rowoff + c] = f2bf(o);
      }
    }
  }
}

// ========== MFMA GEMM (32x256 tile, full H row) + residual + LayerNorm ==========
// 256 threads = 4 waves 1x4 (wave w -> cols w*64). Nn == H_ == 256 fixed.
// EPI: 0 = PV-LN: residual bf16, out fp32 + bf16
//      1 = FFN2-LN: +bias, residual fp32, out bf16(mask*LN)
//      2 = FFN2-LN last: +bias, residual fp32, out fp32 mask*LN
template<int EPI>
__global__ __launch_bounds__(256) void gemm_ln_k(
    const unsigned short* __restrict__ A, const unsigned short* __restrict__ Bm,
    const float* __restrict__ bias, const float* __restrict__ masks,
    const unsigned short* __restrict__ resb, const float* __restrict__ resf,
    float* __restrict__ outf, unsigned short* __restrict__ outb,
    int K, int lda, int ldb, long sA, long sB) {
  __shared__ __align__(16) unsigned short As[32 * 32];
  __shared__ __align__(16) unsigned short Bs[256 * 32];
  __shared__ float red[4][32][2];
  const int b = blockIdx.z;
  const int t = threadIdx.x;
  const int wave = t >> 6, lane = t & 63;
  const int quad = lane >> 4, l15 = lane & 15;
  const int m0 = blockIdx.y * 32;
  const int srow = lane >> 2;
  const int kc = KC_STAGE(lane);
  const int pos8 = (lane & 3) * 8;

  const unsigned short* pa = A + (size_t)b * sA + (size_t)(m0 + wave * 16 + srow) * lda + kc; // waves 0,1
  unsigned short* la = &As[(wave * 16 + srow) * 32 + pos8];
  const unsigned short* pb = Bm + (size_t)b * sB + (size_t)(wave * 16 + srow) * ldb + kc;     // + c*64 rows
  unsigned short* lb = &Bs[(wave * 16 + srow) * 32 + pos8];

  f32x4 acc[2][4];
#pragma unroll
  for (int i = 0; i < 2; ++i)
#pragma unroll
    for (int j = 0; j < 4; ++j) acc[i][j] = (f32x4){0.f, 0.f, 0.f, 0.f};

  const int soff = KC_READ(quad, l15);
  for (int k0 = 0; k0 < K; k0 += 32) {
    if (wave < 2) async16(pa + k0, la);
#pragma unroll
    for (int c = 0; c < 4; ++c)
      async16(pb + (size_t)c * 64 * ldb + k0, lb + c * 64 * 32);
    __syncthreads();
    bf16x8 af[2], bfr[4];
#pragma unroll
    for (int i = 0; i < 2; ++i)
      af[i] = *(const bf16x8*)&As[(i * 16 + l15) * 32 + soff];
#pragma unroll
    for (int j = 0; j < 4; ++j)
      bfr[j] = *(const bf16x8*)&Bs[(wave * 64 + j * 16 + l15) * 32 + soff];
#pragma unroll
    for (int i = 0; i < 2; ++i)
#pragma unroll
      for (int j = 0; j < 4; ++j)
        acc[i][j] = __builtin_amdgcn_mfma_f32_16x16x32_bf16(af[i], bfr[j], acc[i][j], 0, 0, 0);
    __syncthreads();
  }

  float bv[4];
  if (EPI >= 1) {
#pragma unroll
    for (int j = 0; j < 4; ++j) bv[j] = bias[wave * 64 + j * 16 + l15];
  }
#pragma unroll
  for (int i = 0; i < 2; ++i) {
#pragma unroll
    for (int r = 0; r < 4; ++r) {
      const int mloc = i * 16 + quad * 4 + r;
      const long grow = (long)b * N_ + m0 + mloc;
      float s = 0.f, q = 0.f;
#pragma unroll
      for (int j = 0; j < 4; ++j) {
        const int c = wave * 64 + j * 16 + l15;
        float v = acc[i][j][r];
        if (EPI >= 1) v += bv[j];
        v += (EPI == 0) ? bf2f(resb[grow * H_ + c]) : resf[grow * H_ + c];
        acc[i][j][r] = v;
        s += v; q += v * v;
      }
#pragma unroll
      for (int off = 1; off < 16; off <<= 1) {
        s += __shfl_xor(s, off);
        q += __shfl_xor(q, off);
      }
      if (l15 == 0) { red[wave][mloc][0] = s; red[wave][mloc][1] = q; }
    }
  }
  __syncthreads();
#pragma unroll
  for (int i = 0; i < 2; ++i) {
#pragma unroll
    for (int r = 0; r < 4; ++r) {
      const int mloc = i * 16 + quad * 4 + r;
      const long grow = (long)b * N_ + m0 + mloc;
      float S = red[0][mloc][0] + red[1][mloc][0] + red[2][mloc][0] + red[3][mloc][0];
      float Q = red[0][mloc][1] + red[1][mloc][1] + red[2][mloc][1] + red[3][mloc][1];
      float mu = S * (1.f / H_);
      float var = Q * (1.f / H_) - mu * mu;
      float inv = 1.f / sqrtf(var + EPSF);
      float mval = (EPI >= 1) ? masks[grow] : 0.f;
#pragma unroll
      for (int j = 0; j < 4; ++j) {
        const int c = wave * 64 + j * 16 + l15;
        float o = (acc[i][j][r] - mu) * inv;
        if (EPI == 0) {
          outf[grow * H_ + c] = o;
          outb[grow * H_ + c] = f2bf(o);
        } else if (EPI == 1) {
          outb[grow * H_ + c] = f2bf(o * mval);
        } else {
          outf[grow * H_ + c] = o * mval;
        }
      }
    }
  }
}

extern "C" void kernel_launch(void* const* d_in, const int* in_sizes, int n_in,
                              void* d_out, int out_size, void* d_ws, size_t ws_size,
                              hipStream_t stream) {
  const float* features = (const float*)d_in[0];
  const float* masks    = (const float*)d_in[1];
  const float* guide    = (const float*)d_in[2];
  const float* prior    = (const float*)d_in[3];
  const float* WQ       = (const float*)d_in[4];
  const float* WK       = (const float*)d_in[5];
  const float* WV       = (const float*)d_in[6];
  const float* W1       = (const float*)d_in[7];
  const float* b1       = (const float*)d_in[8];
  const float* W2       = (const float*)d_in[9];
  const float* b2       = (const float*)d_in[10];

  float* out     = (float*)d_out;
  float* out_x   = out;
  float* out_att = out + (size_t)BN_ * H_;

  char* w = (char*)d_ws;
  float* post = (float*)w;                     w += (size_t)BN_ * H_ * 4;
  unsigned short* f_bf   = (unsigned short*)w; w += (size_t)BN_ * H_ * 2;
  unsigned short* qk_bf  = (unsigned short*)w; w += (size_t)BN_ * 2 * H_ * 2;
  unsigned short* post_bf= (unsigned short*)w; w += (size_t)BN_ * H_ * 2;
  unsigned short* vT     = (unsigned short*)w; w += (size_t)BN_ * H_ * 2;
  unsigned short* att_bf = (unsigned short*)w; w += (size_t)B_ * N_ * N_ * 2;
  unsigned short* wqk_bf = (unsigned short*)w; w += (size_t)S_ * 2 * HH_ * 2;
  unsigned short* wv_bf  = (unsigned short*)w; w += (size_t)S_ * HH_ * 2;
  unsigned short* w1_bf  = (unsigned short*)w; w += (size_t)S_ * HH_ * 2;
  unsigned short* w2_bf  = (unsigned short*)w; w += (size_t)S_ * HH_ * 2;
  unsigned short* t1_bf  = qk_bf;   // qk dead after ls_k; t1 dead before next qk write

  dim3 blk(256);
  dim3 g_cvt(5 * S_ * HH_ / 1024);
  dim3 g_ew(BN_ * H_ / 1024);
  dim3 g_att((size_t)B_ * N_ * N_ / 1024);
  dim3 g_qkp(4, BN_ / 128, 1);                 // QK fused proj: Nn=512
  dim3 g_ls(1, N_ / 64, B_);                   // fused logits+softmax
  dim3 g_vt(4, 2, B_);                         // vT: Nn=512, M=256
  dim3 g_f1(2, BN_ / 128, 1);                  // FFN1: Nn=256
  dim3 g_pv(1, N_ / 32, B_);                   // PV-LN: 32-row blocks
  dim3 g_f2(1, BN_ / 32, 1);                   // FFN2-LN

  cvt_all_k<<<g_cvt, blk, 0, stream>>>(WQ, WK, WV, W1, W2, wqk_bf, wv_bf, w1_bf, w2_bf);
  mask_mul_k<<<g_ew, blk, 0, stream>>>(features, masks, f_bf);

  const long sLG = (long)N_ * N_;
  const long sF  = (long)N_ * H_;
  const long sVT = (long)H_ * N_;

  for (int i = 0; i < S_; ++i) {
    float* att = out_att + (size_t)i * B_ * N_ * N_;
    if (i == 0) {
      copy_cvt_k<<<g_att, blk, 0, stream>>>(prior, att, att_bf);
    } else {
      // qk = f @ [WQ;WK]^T  -> bf16 [BN][512]
      mfma_gemm_k<0><<<g_qkp, blk, 0, stream>>>(f_bf, wqk_bf + (size_t)i * 2 * HH_,
          nullptr, qk_bf, H_, 2 * H_, H_, H_, 0, 0, 0);
      // att = softmax(q@k^T*scale - masks - guide_inf)  (fused)
      ls_k<<<g_ls, dim3(512), 0, stream>>>(qk_bf, masks, guide, att, att_bf);
    }
    // vT[b][h][n] = WV[i] @ f[b]^T  -> bf16 [B][H][N]
    mfma_gemm_k<0><<<g_vt, blk, 0, stream>>>(wv_bf + (size_t)i * HH_, f_bf,
        nullptr, vT, H_, N_, H_, H_, 0, sF, sVT);
    // post = LN(att @ v + f)  -> fp32 + bf16
    gemm_ln_k<0><<<g_pv, blk, 0, stream>>>(att_bf, vT, nullptr, nullptr,
        f_bf, nullptr, post, post_bf, N_, N_, N_, sLG, sVT);
    // t1 = relu(post @ W1^T + b1) -> bf16
    mfma_gemm_k<3><<<g_f1, blk, 0, stream>>>(post_bf, w1_bf + (size_t)i * HH_,
        b1 + (size_t)i * H_, t1_bf, H_, H_, H_, H_, 0, 0, 0);
    // x = LN(t1 @ W2^T + b2 + post); emit f_bf (i<2) or out_x (i==2)
    if (i < S_ - 1) {
      gemm_ln_k<1><<<g_f2, blk, 0, stream>>>(t1_bf, w2_bf + (size_t)i * HH_,
          b2 + (size_t)i * H_, masks, nullptr, post, nullptr, f_bf, H_, H_, H_, 0, 0);
    } else {
      gemm_ln_k<2><<<g_f2, blk, 0, stream>>>(t1_bf, w2_bf + (size_t)i * HH_,
          b2 + (size_t)i * H_, masks, nullptr, post, out_x, nullptr, H_, H_, H_, 0, 0);
    }
  }
}

// Round 5
// 404.707 us; speedup vs baseline: 2.7126x; 1.1099x over previous
//
#include <hip/hip_runtime.h>
#include <cstdint>
#include <cstddef>

#define B_ 32
#define N_ 512
#define H_ 256
#define S_ 3
#define BN_ (B_*N_)            // 16384
#define HH_ (H_*H_)            // 65536
#define BIGF 3.4028234e+38f
#define EPSF 1e-5f

typedef __bf16 bf16x8 __attribute__((ext_vector_type(8)));
typedef float  f32x4  __attribute__((ext_vector_type(4)));

typedef const void __attribute__((address_space(1)))* gas_t;
typedef void __attribute__((address_space(3)))* las_t;

// async global->LDS, 16B per lane. LDS dest must be wave-uniform base + lane*16.
__device__ __forceinline__ void async16(const unsigned short* g, unsigned short* l) {
  __builtin_amdgcn_global_load_lds((gas_t)g, (las_t)l, 16, 0, 0);
}

__device__ __forceinline__ unsigned short f2bf(float f) {
  __bf16 h = (__bf16)f;
  unsigned short s;
  __builtin_memcpy(&s, &h, 2);
  return s;
}
__device__ __forceinline__ float bf2f(unsigned short u) {
  unsigned int v = ((unsigned int)u) << 16;
  float f;
  __builtin_memcpy(&f, &v, 4);
  return f;
}

// XOR-swizzle for 32-short (64B) LDS rows, 4 chunks of 8 shorts.
#define KC_STAGE(lane) ((((lane) & 3) ^ (((lane) >> 3) & 3)) * 8)
#define KC_READ(quad, l15) ((((quad) ^ (((l15) >> 1) & 3))) * 8)

// ------------- all 5 weight tensors -> bf16 in one dispatch -------------
__global__ __launch_bounds__(256) void cvt_all_k(
    const float* __restrict__ WQ, const float* __restrict__ WK,
    const float* __restrict__ WV, const float* __restrict__ W1,
    const float* __restrict__ W2,
    unsigned short* __restrict__ wqk, unsigned short* __restrict__ wv,
    unsigned short* __restrict__ w1, unsigned short* __restrict__ w2) {
  const int per = S_ * HH_ / 4;
  int gi = blockIdx.x * 256 + threadIdx.x;
  int which = gi / per;
  int e4 = gi - which * per;
  float4 v;
  if      (which == 0) v = ((const float4*)WQ)[e4];
  else if (which == 1) v = ((const float4*)WK)[e4];
  else if (which == 2) v = ((const float4*)WV)[e4];
  else if (which == 3) v = ((const float4*)W1)[e4];
  else                 v = ((const float4*)W2)[e4];
  ushort4 o;
  o.x = f2bf(v.x); o.y = f2bf(v.y); o.z = f2bf(v.z); o.w = f2bf(v.w);
  int e = e4 * 4;
  if (which <= 1) {
    int L = e / HH_, off = e - L * HH_;
    *(ushort4*)&wqk[(size_t)L * 2 * HH_ + (which == 1 ? HH_ : 0) + off] = o;
  } else if (which == 2) ((ushort4*)wv)[e4] = o;
  else if   (which == 3) ((ushort4*)w1)[e4] = o;
  else                   ((ushort4*)w2)[e4] = o;
}

// ------------- f_bf = bf16(x * mask_row) -------------
__global__ __launch_bounds__(256) void mask_mul_k(
    const float* __restrict__ x, const float* __restrict__ masks,
    unsigned short* __restrict__ fb) {
  int i = blockIdx.x * 256 + threadIdx.x;
  int row = i >> 6;
  float m = masks[row];
  float4 v = ((const float4*)x)[i];
  ushort4 o;
  o.x = f2bf(v.x * m); o.y = f2bf(v.y * m); o.z = f2bf(v.z * m); o.w = f2bf(v.w * m);
  ((ushort4*)fb)[i] = o;
}

// ================= MFMA GEMM (128x128, BK=32, async staging), bf16 out =================
// C = A(bf16,[m][k],lda) @ B(bf16,[n][k],ldb)^T
__global__ __launch_bounds__(256) void mfma_gemm_k(
    const unsigned short* __restrict__ A, const unsigned short* __restrict__ Bm,
    unsigned short* __restrict__ Cb,
    int K, int Nn, int lda, int ldb, long sA, long sB, long sC) {
  __shared__ __align__(16) unsigned short As[128 * 32];
  __shared__ __align__(16) unsigned short Bs[128 * 32];
  const int b = blockIdx.z;
  const int t = threadIdx.x;
  const int wave = t >> 6, lane = t & 63;
  const int wm = wave >> 1, wn = wave & 1;
  const int quad = lane >> 4, l15 = lane & 15;
  const int m0 = blockIdx.y * 128, n0 = blockIdx.x * 128;
  const int srow = lane >> 2;
  const int kc = KC_STAGE(lane);
  const int pos8 = (lane & 3) * 8;

  const unsigned short* pa0 = A + (size_t)b * sA + (size_t)(m0 + wave * 32 + srow) * lda + kc;
  const unsigned short* pa1 = pa0 + 16 * (size_t)lda;
  const unsigned short* pb0 = Bm + (size_t)b * sB + (size_t)(n0 + wave * 32 + srow) * ldb + kc;
  const unsigned short* pb1 = pb0 + 16 * (size_t)ldb;
  unsigned short* la0 = &As[(wave * 32 + srow) * 32 + pos8];
  unsigned short* la1 = la0 + 16 * 32;
  unsigned short* lb0 = &Bs[(wave * 32 + srow) * 32 + pos8];
  unsigned short* lb1 = lb0 + 16 * 32;

  f32x4 acc[4][4];
#pragma unroll
  for (int i = 0; i < 4; ++i)
#pragma unroll
    for (int j = 0; j < 4; ++j) acc[i][j] = (f32x4){0.f, 0.f, 0.f, 0.f};

  const int soff = KC_READ(quad, l15);
  for (int k0 = 0; k0 < K; k0 += 32) {
    async16(pa0 + k0, la0); async16(pa1 + k0, la1);
    async16(pb0 + k0, lb0); async16(pb1 + k0, lb1);
    __syncthreads();
    bf16x8 af[4], bfr[4];
#pragma unroll
    for (int i = 0; i < 4; ++i)
      af[i] = *(const bf16x8*)&As[(wm * 64 + i * 16 + l15) * 32 + soff];
#pragma unroll
    for (int j = 0; j < 4; ++j)
      bfr[j] = *(const bf16x8*)&Bs[(wn * 64 + j * 16 + l15) * 32 + soff];
#pragma unroll
    for (int i = 0; i < 4; ++i)
#pragma unroll
      for (int j = 0; j < 4; ++j)
        acc[i][j] = __builtin_amdgcn_mfma_f32_16x16x32_bf16(af[i], bfr[j], acc[i][j], 0, 0, 0);
    __syncthreads();
  }

#pragma unroll
  for (int i = 0; i < 4; ++i) {
    const int rbase = m0 + wm * 64 + i * 16 + quad * 4;
#pragma unroll
    for (int j = 0; j < 4; ++j) {
      const int c = n0 + wn * 64 + j * 16 + l15;
#pragma unroll
      for (int r = 0; r < 4; ++r)
        Cb[(size_t)b * sC + (size_t)(rbase + r) * Nn + c] = f2bf(acc[i][j][r]);
    }
  }
}

// ========== Fused [QK^T + mask/guide + softmax | prior-copy] + P@V^T + residual + LN ==========
// 64 q-rows per block, 512 threads (8 waves). PRIOR=1: P comes from prior (layer 0).
// Phase A wave grid 2x4 (rows 32 x cols 128); Phase B wave grid 2x4 (rows 32 x cols 64).
// Outputs: att fp32 (d_out slice), post fp32 + post_bf (LN(P@V + f)).
template<int PRIOR>
__global__ __launch_bounds__(512) void ls_pv_k(
    const unsigned short* __restrict__ qk, const float* __restrict__ prior,
    const float* __restrict__ masks, const float* __restrict__ guide,
    const unsigned short* __restrict__ vT, const unsigned short* __restrict__ resb,
    float* __restrict__ att, float* __restrict__ post, unsigned short* __restrict__ postb) {
  __shared__ __align__(16) unsigned short As[64 * 32];      // 4 KB
  __shared__ __align__(16) unsigned short Bs[512 * 32];     // 32 KB (reused phase B: 256 rows)
  __shared__ __align__(16) unsigned short Ps[64 * 520];     // 66.5 KB, padded rows
  __shared__ float red[4][64][2];                           // 2 KB
  const int b = blockIdx.z;
  const int t = threadIdx.x;
  const int wave = t >> 6, lane = t & 63;
  const int quad = lane >> 4, l15 = lane & 15;
  const int m0 = blockIdx.y * 64;
  const int srow = lane >> 2;
  const int kc = KC_STAGE(lane);
  const int pos8 = (lane & 3) * 8;
  const int soff = KC_READ(quad, l15);

  if (PRIOR) {
    // ---- Phase A': copy prior -> att out, convert -> Ps ----
    const float* src = prior + ((size_t)b * N_ + m0) * N_;
    float*       dst = att   + ((size_t)b * N_ + m0) * N_;
#pragma unroll
    for (int s = 0; s < 16; ++s) {
      int idx4 = s * 512 + t;
      float4 v = ((const float4*)src)[idx4];
      ((float4*)dst)[idx4] = v;
      int row = idx4 >> 7, col4 = idx4 & 127;
      ushort4 o;
      o.x = f2bf(v.x); o.y = f2bf(v.y); o.z = f2bf(v.z); o.w = f2bf(v.w);
      *(ushort4*)&Ps[row * 520 + col4 * 4] = o;
    }
    __syncthreads();
  } else {
    // ---- Phase A: QK^T ----
    const int wm = wave >> 2, wn = wave & 3;
    const int ld = 2 * H_;
    const unsigned short* base = qk + (size_t)b * N_ * ld;
    const unsigned short* pa = base + (size_t)(m0 + wave * 16 + srow) * ld + kc;   // waves 0..3
    unsigned short* la = &As[(wave * 16 + srow) * 32 + pos8];
    const unsigned short* pb = base + H_ + (size_t)(wave * 64 + srow) * ld + kc;
    unsigned short* lb = &Bs[(wave * 64 + srow) * 32 + pos8];

    f32x4 acc[2][8];
#pragma unroll
    for (int i = 0; i < 2; ++i)
#pragma unroll
      for (int j = 0; j < 8; ++j) acc[i][j] = (f32x4){0.f, 0.f, 0.f, 0.f};

    for (int k0 = 0; k0 < H_; k0 += 32) {
      if (wave < 4) async16(pa + k0, la);
#pragma unroll
      for (int c = 0; c < 4; ++c)
        async16(pb + (size_t)c * 16 * ld + k0, lb + c * 16 * 32);
      __syncthreads();
      bf16x8 af[2], bfr[8];
#pragma unroll
      for (int i = 0; i < 2; ++i)
        af[i] = *(const bf16x8*)&As[(wm * 32 + i * 16 + l15) * 32 + soff];
#pragma unroll
      for (int j = 0; j < 8; ++j)
        bfr[j] = *(const bf16x8*)&Bs[(wn * 128 + j * 16 + l15) * 32 + soff];
#pragma unroll
      for (int i = 0; i < 2; ++i)
#pragma unroll
        for (int j = 0; j < 8; ++j)
          acc[i][j] = __builtin_amdgcn_mfma_f32_16x16x32_bf16(af[i], bfr[j], acc[i][j], 0, 0, 0);
      __syncthreads();
    }

    // logits + row-max
    float am[8];
#pragma unroll
    for (int j = 0; j < 8; ++j) {
      float mv = masks[(size_t)b * N_ + wn * 128 + j * 16 + l15];
      am[j] = (mv != 0.f) ? 0.f : BIGF;
    }
#pragma unroll
    for (int i = 0; i < 2; ++i) {
#pragma unroll
      for (int r = 0; r < 4; ++r) {
        const int mloc = wm * 32 + i * 16 + quad * 4 + r;
        const float* gr = guide + ((size_t)b * N_ + m0 + mloc) * N_;
        float mx = -BIGF;
#pragma unroll
        for (int j = 0; j < 8; ++j) {
          const int c = wn * 128 + j * 16 + l15;
          float g = gr[c];
          float v = acc[i][j][r] * 0.0625f - am[j] - ((g != 0.f) ? 0.f : BIGF);
          acc[i][j][r] = v;
          mx = fmaxf(mx, v);
        }
#pragma unroll
        for (int off = 1; off < 16; off <<= 1) mx = fmaxf(mx, __shfl_xor(mx, off));
        if (l15 == 0) red[wn][mloc][0] = mx;
      }
    }
    __syncthreads();
    // exp + row-sum
#pragma unroll
    for (int i = 0; i < 2; ++i) {
#pragma unroll
      for (int r = 0; r < 4; ++r) {
        const int mloc = wm * 32 + i * 16 + quad * 4 + r;
        float M = fmaxf(fmaxf(red[0][mloc][0], red[1][mloc][0]),
                        fmaxf(red[2][mloc][0], red[3][mloc][0]));
        float s = 0.f;
#pragma unroll
        for (int j = 0; j < 8; ++j) {
          float e = __expf(acc[i][j][r] - M);
          acc[i][j][r] = e;
          s += e;
        }
#pragma unroll
        for (int off = 1; off < 16; off <<= 1) s += __shfl_xor(s, off);
        if (l15 == 0) red[wn][mloc][1] = s;
      }
    }
    __syncthreads();
    // normalize -> att fp32 + Ps bf16
#pragma unroll
    for (int i = 0; i < 2; ++i) {
#pragma unroll
      for (int r = 0; r < 4; ++r) {
        const int mloc = wm * 32 + i * 16 + quad * 4 + r;
        float S = red[0][mloc][1] + red[1][mloc][1] + red[2][mloc][1] + red[3][mloc][1];
        float inv = 1.f / S;
        const size_t rowoff = ((size_t)b * N_ + m0 + mloc) * N_;
#pragma unroll
        for (int j = 0; j < 8; ++j) {
          const int c = wn * 128 + j * 16 + l15;
          float o = acc[i][j][r] * inv;
          att[rowoff + c] = o;
          Ps[mloc * 520 + c] = f2bf(o);
        }
      }
    }
    __syncthreads();
  }

  // ---- Phase B: post = LN(P @ vT^T + f) ----
  const int wm2 = wave >> 2, wn2 = wave & 3;
  const unsigned short* vb = vT + (size_t)b * H_ * N_;
  const unsigned short* pv0 = vb + (size_t)(wave * 16 + srow) * N_ + kc;  // rows 0..127
  const unsigned short* pv1 = pv0 + (size_t)128 * N_;                     // rows 128..255
  unsigned short* lv0 = &Bs[(wave * 16 + srow) * 32 + pos8];
  unsigned short* lv1 = lv0 + 128 * 32;

  f32x4 acc2[2][4];
#pragma unroll
  for (int i = 0; i < 2; ++i)
#pragma unroll
    for (int j = 0; j < 4; ++j) acc2[i][j] = (f32x4){0.f, 0.f, 0.f, 0.f};

  for (int k0 = 0; k0 < N_; k0 += 32) {
    async16(pv0 + k0, lv0);
    async16(pv1 + k0, lv1);
    __syncthreads();
    bf16x8 af[2], bfr[4];
#pragma unroll
    for (int i = 0; i < 2; ++i)
      af[i] = *(const bf16x8*)&Ps[(wm2 * 32 + i * 16 + l15) * 520 + k0 + quad * 8];
#pragma unroll
    for (int j = 0; j < 4; ++j)
      bfr[j] = *(const bf16x8*)&Bs[(wn2 * 64 + j * 16 + l15) * 32 + soff];
#pragma unroll
    for (int i = 0; i < 2; ++i)
#pragma unroll
      for (int j = 0; j < 4; ++j)
        acc2[i][j] = __builtin_amdgcn_mfma_f32_16x16x32_bf16(af[i], bfr[j], acc2[i][j], 0, 0, 0);
    __syncthreads();
  }

  // residual + LN
#pragma unroll
  for (int i = 0; i < 2; ++i) {
#pragma unroll
    for (int r = 0; r < 4; ++r) {
      const int mloc = wm2 * 32 + i * 16 + quad * 4 + r;
      const long grow = (long)b * N_ + m0 + mloc;
      float s = 0.f, q = 0.f;
#pragma unroll
      for (int j = 0; j < 4; ++j) {
        const int c = wn2 * 64 + j * 16 + l15;
        float v = acc2[i][j][r] + bf2f(resb[grow * H_ + c]);
        acc2[i][j][r] = v;
        s += v; q += v * v;
      }
#pragma unroll
      for (int off = 1; off < 16; off <<= 1) {
        s += __shfl_xor(s, off);
        q += __shfl_xor(q, off);
      }
      if (l15 == 0) { red[wn2][mloc][0] = s; red[wn2][mloc][1] = q; }
    }
  }
  __syncthreads();
#pragma unroll
  for (int i = 0; i < 2; ++i) {
#pragma unroll
    for (int r = 0; r < 4; ++r) {
      const int mloc = wm2 * 32 + i * 16 + quad * 4 + r;
      const long grow = (long)b * N_ + m0 + mloc;
      float S = red[0][mloc][0] + red[1][mloc][0] + red[2][mloc][0] + red[3][mloc][0];
      float Q = red[0][mloc][1] + red[1][mloc][1] + red[2][mloc][1] + red[3][mloc][1];
      float mu = S * (1.f / H_);
      float var = Q * (1.f / H_) - mu * mu;
      float inv = 1.f / sqrtf(var + EPSF);
#pragma unroll
      for (int j = 0; j < 4; ++j) {
        const int c = wn2 * 64 + j * 16 + l15;
        float o = (acc2[i][j][r] - mu) * inv;
        post[grow * H_ + c] = o;
        postb[grow * H_ + c] = f2bf(o);
      }
    }
  }
}

// ========== Fused FFN: x = LN(relu(post@W1^T+b1)@W2^T + b2 + post), out = mask*x ==========
// 64 rows per block, 512 threads (8 waves, 2x4). t1 lives in LDS between phases.
// LAST=0: out f_bf bf16; LAST=1: out out_x fp32.
template<int LAST>
__global__ __launch_bounds__(512) void ffn_k(
    const unsigned short* __restrict__ postb, const float* __restrict__ postf,
    const unsigned short* __restrict__ w1, const float* __restrict__ b1,
    const unsigned short* __restrict__ w2, const float* __restrict__ b2,
    const float* __restrict__ masks,
    unsigned short* __restrict__ fb, float* __restrict__ outx) {
  __shared__ __align__(16) unsigned short As[64 * 32];    // 4 KB
  __shared__ __align__(16) unsigned short Bs[256 * 32];   // 16 KB
  __shared__ __align__(16) unsigned short T1[64 * 264];   // 33 KB, padded rows
  __shared__ float red[4][64][2];                         // 2 KB
  const int t = threadIdx.x;
  const int wave = t >> 6, lane = t & 63;
  const int wm = wave >> 2, wn = wave & 3;
  const int quad = lane >> 4, l15 = lane & 15;
  const int m0 = blockIdx.y * 64;
  const int srow = lane >> 2;
  const int kc = KC_STAGE(lane);
  const int pos8 = (lane & 3) * 8;
  const int soff = KC_READ(quad, l15);

  const unsigned short* pa = postb + (size_t)(m0 + wave * 16 + srow) * H_ + kc;  // waves 0..3
  unsigned short* la = &As[(wave * 16 + srow) * 32 + pos8];
  unsigned short* lb0 = &Bs[(wave * 16 + srow) * 32 + pos8];
  unsigned short* lb1 = lb0 + 128 * 32;

  // ---- Phase 1: t1 = relu(post @ W1^T + b1) -> T1 (LDS) ----
  {
    const unsigned short* pb0 = w1 + (size_t)(wave * 16 + srow) * H_ + kc;
    const unsigned short* pb1 = pb0 + (size_t)128 * H_;
    f32x4 acc[2][4];
#pragma unroll
    for (int i = 0; i < 2; ++i)
#pragma unroll
      for (int j = 0; j < 4; ++j) acc[i][j] = (f32x4){0.f, 0.f, 0.f, 0.f};
    for (int k0 = 0; k0 < H_; k0 += 32) {
      if (wave < 4) async16(pa + k0, la);
      async16(pb0 + k0, lb0);
      async16(pb1 + k0, lb1);
      __syncthreads();
      bf16x8 af[2], bfr[4];
#pragma unroll
      for (int i = 0; i < 2; ++i)
        af[i] = *(const bf16x8*)&As[(wm * 32 + i * 16 + l15) * 32 + soff];
#pragma unroll
      for (int j = 0; j < 4; ++j)
        bfr[j] = *(const bf16x8*)&Bs[(wn * 64 + j * 16 + l15) * 32 + soff];
#pragma unroll
      for (int i = 0; i < 2; ++i)
#pragma unroll
        for (int j = 0; j < 4; ++j)
          acc[i][j] = __builtin_amdgcn_mfma_f32_16x16x32_bf16(af[i], bfr[j], acc[i][j], 0, 0, 0);
      __syncthreads();
    }
    float bv[4];
#pragma unroll
    for (int j = 0; j < 4; ++j) bv[j] = b1[wn * 64 + j * 16 + l15];
#pragma unroll
    for (int i = 0; i < 2; ++i) {
#pragma unroll
      for (int r = 0; r < 4; ++r) {
        const int mloc = wm * 32 + i * 16 + quad * 4 + r;
#pragma unroll
        for (int j = 0; j < 4; ++j) {
          const int c = wn * 64 + j * 16 + l15;
          T1[mloc * 264 + c] = f2bf(fmaxf(acc[i][j][r] + bv[j], 0.f));
        }
      }
    }
  }
  __syncthreads();

  // ---- Phase 2: x = LN(T1 @ W2^T + b2 + post) * mask ----
  {
    const unsigned short* pb0 = w2 + (size_t)(wave * 16 + srow) * H_ + kc;
    const unsigned short* pb1 = pb0 + (size_t)128 * H_;
    f32x4 acc[2][4];
#pragma unroll
    for (int i = 0; i < 2; ++i)
#pragma unroll
      for (int j = 0; j < 4; ++j) acc[i][j] = (f32x4){0.f, 0.f, 0.f, 0.f};
    for (int k0 = 0; k0 < H_; k0 += 32) {
      async16(pb0 + k0, lb0);
      async16(pb1 + k0, lb1);
      __syncthreads();
      bf16x8 af[2], bfr[4];
#pragma unroll
      for (int i = 0; i < 2; ++i)
        af[i] = *(const bf16x8*)&T1[(wm * 32 + i * 16 + l15) * 264 + k0 + quad * 8];
#pragma unroll
      for (int j = 0; j < 4; ++j)
        bfr[j] = *(const bf16x8*)&Bs[(wn * 64 + j * 16 + l15) * 32 + soff];
#pragma unroll
      for (int i = 0; i < 2; ++i)
#pragma unroll
        for (int j = 0; j < 4; ++j)
          acc[i][j] = __builtin_amdgcn_mfma_f32_16x16x32_bf16(af[i], bfr[j], acc[i][j], 0, 0, 0);
      __syncthreads();
    }
    float bv[4];
#pragma unroll
    for (int j = 0; j < 4; ++j) bv[j] = b2[wn * 64 + j * 16 + l15];
#pragma unroll
    for (int i = 0; i < 2; ++i) {
#pragma unroll
      for (int r = 0; r < 4; ++r) {
        const int mloc = wm * 32 + i * 16 + quad * 4 + r;
        const long grow = (long)m0 + mloc;
        float s = 0.f, q = 0.f;
#pragma unroll
        for (int j = 0; j < 4; ++j) {
          const int c = wn * 64 + j * 16 + l15;
          float v = acc[i][j][r] + bv[j] + postf[grow * H_ + c];
          acc[i][j][r] = v;
          s += v; q += v * v;
        }
#pragma unroll
        for (int off = 1; off < 16; off <<= 1) {
          s += __shfl_xor(s, off);
          q += __shfl_xor(q, off);
        }
        if (l15 == 0) { red[wn][mloc][0] = s; red[wn][mloc][1] = q; }
      }
    }
    __syncthreads();
#pragma unroll
    for (int i = 0; i < 2; ++i) {
#pragma unroll
      for (int r = 0; r < 4; ++r) {
        const int mloc = wm * 32 + i * 16 + quad * 4 + r;
        const long grow = (long)m0 + mloc;
        float S = red[0][mloc][0] + red[1][mloc][0] + red[2][mloc][0] + red[3][mloc][0];
        float Q = red[0][mloc][1] + red[1][mloc][1] + red[2][mloc][1] + red[3][mloc][1];
        float mu = S * (1.f / H_);
        float var = Q * (1.f / H_) - mu * mu;
        float inv = 1.f / sqrtf(var + EPSF);
        float mval = masks[grow];
#pragma unroll
        for (int j = 0; j < 4; ++j) {
          const int c = wn * 64 + j * 16 + l15;
          float o = (acc[i][j][r] - mu) * inv * mval;
          if (LAST) outx[grow * H_ + c] = o;
          else      fb[grow * H_ + c] = f2bf(o);
        }
      }
    }
  }
}

extern "C" void kernel_launch(void* const* d_in, const int* in_sizes, int n_in,
                              void* d_out, int out_size, void* d_ws, size_t ws_size,
                              hipStream_t stream) {
  const float* features = (const float*)d_in[0];
  const float* masks    = (const float*)d_in[1];
  const float* guide    = (const float*)d_in[2];
  const float* prior    = (const float*)d_in[3];
  const float* WQ       = (const float*)d_in[4];
  const float* WK       = (const float*)d_in[5];
  const float* WV       = (const float*)d_in[6];
  const float* W1       = (const float*)d_in[7];
  const float* b1       = (const float*)d_in[8];
  const float* W2       = (const float*)d_in[9];
  const float* b2       = (const float*)d_in[10];

  float* out     = (float*)d_out;
  float* out_x   = out;
  float* out_att = out + (size_t)BN_ * H_;

  char* w = (char*)d_ws;
  float* post = (float*)w;                     w += (size_t)BN_ * H_ * 4;        // 16 MB
  unsigned short* f_bf   = (unsigned short*)w; w += (size_t)BN_ * H_ * 2;        // 8 MB
  unsigned short* qk_bf  = (unsigned short*)w; w += (size_t)BN_ * 2 * H_ * 2;    // 16 MB
  unsigned short* post_bf= (unsigned short*)w; w += (size_t)BN_ * H_ * 2;        // 8 MB
  unsigned short* vT     = (unsigned short*)w; w += (size_t)BN_ * H_ * 2;        // 8 MB
  unsigned short* wqk_bf = (unsigned short*)w; w += (size_t)S_ * 2 * HH_ * 2;
  unsigned short* wv_bf  = (unsigned short*)w; w += (size_t)S_ * HH_ * 2;
  unsigned short* w1_bf  = (unsigned short*)w; w += (size_t)S_ * HH_ * 2;
  unsigned short* w2_bf  = (unsigned short*)w; w += (size_t)S_ * HH_ * 2;

  dim3 g_cvt(5 * S_ * HH_ / 1024);
  dim3 g_ew(BN_ * H_ / 1024);
  dim3 g_qkp(4, BN_ / 128, 1);                 // QK fused proj: Nn=512
  dim3 g_vt(4, 2, B_);                         // vT: Nn=512, M=256 (h), per batch
  dim3 g_ls(1, N_ / 64, B_);                   // fused logits/softmax + PV + LN
  dim3 g_ffn(1, BN_ / 64, 1);                  // fused FFN + LN

  cvt_all_k<<<g_cvt, 256, 0, stream>>>(WQ, WK, WV, W1, W2, wqk_bf, wv_bf, w1_bf, w2_bf);
  mask_mul_k<<<g_ew, 256, 0, stream>>>(features, masks, f_bf);

  const long sF  = (long)N_ * H_;
  const long sVT = (long)H_ * N_;

  for (int i = 0; i < S_; ++i) {
    float* att = out_att + (size_t)i * B_ * N_ * N_;
    // vT[b][h][n] = WV[i] @ f[b]^T
    mfma_gemm_k<<<g_vt, 256, 0, stream>>>(wv_bf + (size_t)i * HH_, f_bf, vT,
                                          H_, N_, H_, H_, 0, sF, sVT);
    if (i == 0) {
      ls_pv_k<1><<<g_ls, 512, 0, stream>>>(nullptr, prior, nullptr, nullptr,
                                           vT, f_bf, att, post, post_bf);
    } else {
      // qk = f @ [WQ;WK]^T -> bf16 [BN][512]
      mfma_gemm_k<<<g_qkp, 256, 0, stream>>>(f_bf, wqk_bf + (size_t)i * 2 * HH_, qk_bf,
                                             H_, 2 * H_, H_, H_, 0, 0, 0);
      ls_pv_k<0><<<g_ls, 512, 0, stream>>>(qk_bf, nullptr, masks, guide,
                                           vT, f_bf, att, post, post_bf);
    }
    if (i < S_ - 1) {
      ffn_k<0><<<g_ffn, 512, 0, stream>>>(post_bf, post,
          w1_bf + (size_t)i * HH_, b1 + (size_t)i * H_,
          w2_bf + (size_t)i * HH_, b2 + (size_t)i * H_, masks, f_bf, nullptr);
    } else {
      ffn_k<1><<<g_ffn, 512, 0, stream>>>(post_bf, post,
          w1_bf + (size_t)i * HH_, b1 + (size_t)i * H_,
          w2_bf + (size_t)i * HH_, b2 + (size_t)i * H_, masks, nullptr, out_x);
    }
  }
}